// Round 1
// baseline (13302.681 us; speedup 1.0000x reference)
//
#include <hip/hip_runtime.h>
#include <cstddef>

using bf16x8 = __attribute__((ext_vector_type(8))) short;
using f32x4  = __attribute__((ext_vector_type(4))) float;

constexpr int Bb = 128;
constexpr int Tt = 256;
constexpr int Hh = 1024;
constexpr int Oo = 64;
constexpr int NBLK = 200;         // 64 h1 + 64 acc2 + 64 u + 8 out
constexpr int FLAG_STRIDE = 32;   // dwords -> 128B between flags
constexpr int RS = 1048;          // LDS row stride in shorts: 524 dwords ≡ 12 (mod 32)

__device__ __forceinline__ float bf2f(short s) {
  unsigned int u = ((unsigned int)(unsigned short)s) << 16;
  float f;
  __builtin_memcpy(&f, &u, 4);
  return f;
}
__device__ __forceinline__ short f2bf(float f) {
  unsigned int u;
  __builtin_memcpy(&u, &f, 4);
  u += 0x7fffu + ((u >> 16) & 1u);  // round-to-nearest-even
  return (short)(u >> 16);
}
__device__ __forceinline__ bf16x8 as_bf(int4 v) {
  union { int4 i; bf16x8 b; } u; u.i = v; return u.b;
}
__device__ __forceinline__ float ldf(const float* p) {
  return __hip_atomic_load((float*)p, __ATOMIC_RELAXED, __HIP_MEMORY_SCOPE_AGENT);
}
__device__ __forceinline__ void stf(float* p, float v) {
  __hip_atomic_store(p, v, __ATOMIC_RELAXED, __HIP_MEMORY_SCOPE_AGENT);
}
__device__ __forceinline__ unsigned ldu(const unsigned* p) {
  return __hip_atomic_load((unsigned*)p, __ATOMIC_RELAXED, __HIP_MEMORY_SCOPE_AGENT);
}

// Agent-scope (sc1) coherent 16B load — bypasses per-XCD L2, LLC-coherent.
#define LD16A(d, p) asm volatile("global_load_dwordx4 %0, %1, off sc1" \
                                 : "=v"(d) : "v"((const void*)(p)))

// async global->LDS, 16B per lane (cached path; weights are L2-resident).
__device__ __forceinline__ void gll16(const void* g, void* l) {
  __builtin_amdgcn_global_load_lds(
      (const __attribute__((address_space(1))) void*)g,
      (__attribute__((address_space(3))) void*)l, 16, 0, 0);
}

// Stage one 16-row x 1024-col bf16 state slab into LDS: 256 threads x 8 flat
// sc1 loads, then LDS writes. Ends with vmcnt(0) -> at pass entry the
// outstanding-VMEM count is exactly 0 (required for counted vmcnt below).
__device__ __forceinline__ void stage16(short* As, const short* src, int tid) {
  const int row = tid >> 4;          // 0..15
  const int c0  = (tid & 15) * 8;    // shorts
  const short* gp = src + (size_t)row * Hh + c0;
  short* lp = As + row * RS + c0;
  int4 r[8];
#pragma unroll
  for (int j = 0; j < 8; ++j) LD16A(r[j], gp + j * 128);
  asm volatile("s_waitcnt vmcnt(0)" ::: "memory");
#pragma unroll
  for (int j = 0; j < 8; ++j) *(int4*)(lp + j * 128) = r[j];
}

// ---------------------------------------------------------------------------
// NEW: BW-bound weight feed. 16 rows x 128 cols, K=1024, chunked KC=128.
// Each wave stages ITS OWN 32 cols into its private 8KB region of a 3-buffer
// LDS ring via global_load_lds (8 instr/chunk, 3 chunks = 24KB/wave in
// flight), counted vmcnt, NO block barriers in the pass.
// Slot s = wv*512 + j*64 + lane  ->  local col = wv*32 + j*4 + (lane>>4),
// k-subslot = (lane&15) ^ (col&7)   (XOR pre-swizzle of the GLOBAL source;
// read side applies the same XOR -> ds_read_b128 balanced 8 lanes/bank-quad).
// ---------------------------------------------------------------------------
__device__ __forceinline__ void staged_pass(const short* As, short* Bs,
    const short* __restrict__ wslab, int bstride,
    int lm, int q, int wv, f32x4 (&acc)[2]) {
  const short* ga[8];
#pragma unroll
  for (int j = 0; j < 8; ++j) {
    const int colj = wv * 32 + j * 4 + q;
    const int ksub = lm ^ (colj & 7);
    ga[j] = wslab + (size_t)colj * bstride + ksub * 8;
  }
  short* lw = Bs + wv * 4096;   // this wave's 8KB region (shorts) in buffer 0
#define STG(cnk) do {                                                   \
    short* lb = lw + ((cnk) % 3) * 16384;                               \
    _Pragma("unroll")                                                   \
    for (int j = 0; j < 8; ++j)                                         \
      gll16(ga[j] + (cnk) * 128, lb + j * 512);                         \
  } while (0)
  STG(0); STG(1); STG(2);
  const int bro = (lm & 7) << 4;
  const short* bc0 = Bs + (wv * 32 + lm) * 128;        // col row base (n=0)
  const short* bc1 = Bs + (wv * 32 + 16 + lm) * 128;   // n=1
  const short* ar  = As + lm * RS + q * 8;
#pragma unroll
  for (int c = 0; c < 8; ++c) {
    // drain own chunk c: outstanding = 8 * (#chunks staged beyond c)
    if (c < 6)       asm volatile("s_waitcnt vmcnt(16)" ::: "memory");
    else if (c == 6) asm volatile("s_waitcnt vmcnt(8)" ::: "memory");
    else             asm volatile("s_waitcnt vmcnt(0)" ::: "memory");
    const int bufo = (c % 3) * 16384;   // shorts
#pragma unroll
    for (int cc = 0; cc < 4; ++cc) {
      const int koff = (q * 16 + cc * 64) ^ bro;   // byte offset in 256B row
      const bf16x8 a  = as_bf(*(const int4*)(ar + c * 128 + cc * 32));
      const bf16x8 b0 = as_bf(*(const int4*)((const char*)(bc0 + bufo) + koff));
      const bf16x8 b1 = as_bf(*(const int4*)((const char*)(bc1 + bufo) + koff));
      acc[0] = __builtin_amdgcn_mfma_f32_16x16x32_bf16(a, b0, acc[0], 0, 0, 0);
      acc[1] = __builtin_amdgcn_mfma_f32_16x16x32_bf16(a, b1, acc[1], 0, 0, 0);
    }
    if (c < 5) STG(c + 3);
  }
#undef STG
}

// Old direct-load pass, kept for the small 64-col output-head roles.
__device__ __forceinline__ void lds_pass2(const short* As, int lm, int q,
    const short* __restrict__ Bw, int bstride, int colw, f32x4 (&acc)[2]) {
  const short* ap  = As + lm * RS + q * 8;
  const short* bp0 = Bw + (size_t)(colw + lm) * bstride + q * 8;
  const short* bp1 = bp0 + (size_t)16 * bstride;
  int4 b0v[3], b1v[3];
  b0v[0] = *(const int4*)(bp0);      b1v[0] = *(const int4*)(bp1);
  b0v[1] = *(const int4*)(bp0 + 32); b1v[1] = *(const int4*)(bp1 + 32);
#pragma unroll
  for (int c = 0; c < 32; ++c) {
    if (c + 2 < 32) {
      b0v[(c + 2) % 3] = *(const int4*)(bp0 + (c + 2) * 32);
      b1v[(c + 2) % 3] = *(const int4*)(bp1 + (c + 2) * 32);
    }
    const bf16x8 a = as_bf(*(const int4*)(ap + c * 32));
    acc[0] = __builtin_amdgcn_mfma_f32_16x16x32_bf16(a, as_bf(b0v[c % 3]), acc[0], 0, 0, 0);
    acc[1] = __builtin_amdgcn_mfma_f32_16x16x32_bf16(a, as_bf(b1v[c % 3]), acc[1], 0, 0, 0);
  }
}

// Hierarchical RMW-free grid barrier (identical structure to prior rounds).
__device__ __forceinline__ void grid_barrier(unsigned* flags, unsigned* go,
                                             unsigned gen, int bid, int tid) {
  __builtin_amdgcn_s_waitcnt(0);
  __syncthreads();
  if (tid == 0)
    __hip_atomic_store(flags + (size_t)bid * FLAG_STRIDE, gen,
                       __ATOMIC_RELAXED, __HIP_MEMORY_SCOPE_AGENT);
  if (bid == 0) {
    if (tid < 64) {
      const unsigned* f = flags + (size_t)tid * FLAG_STRIDE;
      for (;;) {
        const unsigned a = ldu(f);
        const unsigned b = ldu(f +  64 * FLAG_STRIDE);
        const unsigned c = ldu(f + 128 * FLAG_STRIDE);
        const unsigned d = ldu(f + 192 * FLAG_STRIDE);
        if (__all((a >= gen) && (b >= gen) && (c >= gen) && (d >= gen))) break;
        __builtin_amdgcn_s_sleep(2);
      }
      if (tid == 0)
        __hip_atomic_store(go, gen, __ATOMIC_RELAXED, __HIP_MEMORY_SCOPE_AGENT);
    }
  } else if (tid < 64) {
    while (ldu(go) < gen)
      __builtin_amdgcn_s_sleep(2);
  }
  __syncthreads();
  asm volatile("" ::: "memory");
}

// C/D layout (verified m89/m91): col = lane&15, row = (lane>>4)*4 + reg
#define TL(MB, CW, ACC, ...) do {                                          \
    _Pragma("unroll")                                                      \
    for (int n = 0; n < 2; ++n) {                                          \
      _Pragma("unroll")                                                    \
      for (int r = 0; r < 4; ++r) {                                        \
        const int row = (MB) + q * 4 + r;                                  \
        const int col = (CW) + n * 16 + lm;                                \
        const float z = (ACC)[n][r];                                       \
        __VA_ARGS__;                                                       \
      } } } while (0)

#define ST_BF16_PAIR(BASE, ROW, COL, HV) do {                              \
    const int _ov = __shfl_xor((int)(unsigned short)(HV), 1, 64);          \
    if ((lm & 1) == 0) {                                                   \
      const unsigned _pk = (unsigned)(unsigned short)(HV) | ((unsigned)_ov << 16); \
      __hip_atomic_store((unsigned*)((BASE) + (ROW) * Hh + (COL)), _pk,    \
                         __ATOMIC_RELAXED, __HIP_MEMORY_SCOPE_AGENT);      \
    } } while (0)

#define SET_ACC(ACC, V0, V1) do {                                          \
    (ACC)[0] = (f32x4){(V0), (V0), (V0), (V0)};                            \
    (ACC)[1] = (f32x4){(V1), (V1), (V1), (V1)};                            \
  } while (0)

struct RP {
  short* h1a; short* h1b; short* h2bf;
  float* h2f; float* uf; float* ug1f; float* acc2f; float* o1f;
  const short* prex;
  const short* whh1; const short* wih2; const short* whh2;
  const short* wg; const short* wo1; const short* wo2;
  const float* b_ih2; const float* b_hh2;
  const float* bg; const float* bo1; const float* bo2;
  float* out;
  unsigned* flags;
  unsigned* go;
};

// r9 dataflow, fat-block edition + async-staged weight feed.
//  Phase A: bid 0-63 h1 | 64-127 acc2 | 128-191 u-gate | 192-199 out(t-1)
//  Phase B: bid 0-63 h2 blend | 64-127 ug1 | 192-199 o1 head | others idle
__global__ void __launch_bounds__(256, 1) rnn_kernel(RP p) {
  __shared__ short As[16 * RS];      // 33536 B
  __shared__ short Bs[3 * 16384];    // 98304 B weight-chunk ring (3 x 32KB)
  const int tid = threadIdx.x;
  const int lane = tid & 63;
  const int wv = tid >> 6;
  const int lm = lane & 15;
  const int q = lane >> 4;
  const int bid = blockIdx.x;

  int roleA, roleB, g;
  if      (bid < 64)  { roleA = 0; roleB = 4; g = bid; }
  else if (bid < 128) { roleA = 1; roleB = 5; g = bid - 64; }
  else if (bid < 192) { roleA = 2; roleB = 7; g = bid - 128; }
  else                { roleA = 3; roleB = 6; g = bid - 192; }
  const bool small = (roleA == 3);              // out/o1 blocks: 16r x 64c
  const int mb   = small ? g * 16 : (g >> 3) * 16;
  const int cb   = (g & 7) * 128;               // big-role 128-col slab base
  const int colw = small ? wv * 32 : cb + wv * 32;

  float bA0 = 0.f, bA1 = 0.f, bB0 = 0.f, bB1 = 0.f;
  {
    const int c0 = colw + lm, c1 = colw + 16 + lm;
    if (roleA == 1) { bA0 = p.b_ih2[c0] + p.b_hh2[c0]; bA1 = p.b_ih2[c1] + p.b_hh2[c1]; }
    else if (roleA == 2) { bA0 = p.bg[c0]; bA1 = p.bg[c1]; }
    else if (roleA == 3 && wv < 2) { bA0 = p.bo2[c0]; bA1 = p.bo2[c1]; }
    if (roleB == 6 && wv < 2) { bB0 = p.bo1[c0]; bB1 = p.bo1[c1]; }
  }
  const size_t HS = (size_t)Bb * Hh;

  f32x4 acc[2];
  unsigned gen = 0;
  for (int t = 0; t < Tt; ++t) {
    const short* h1in  = (t & 1) ? p.h1b : p.h1a;
    short*       h1out = (t & 1) ? p.h1a : p.h1b;
    // ---------------- Phase A ----------------
    if (roleA == 0) {
      short prs[2][4];
      const short* pr = p.prex + (size_t)t * HS;
#pragma unroll
      for (int n = 0; n < 2; ++n)
#pragma unroll
        for (int r = 0; r < 4; ++r)
          prs[n][r] = pr[(size_t)(mb + q * 4 + r) * Hh + colw + n * 16 + lm];
      stage16(As, h1in + (size_t)mb * Hh, tid);
      __syncthreads();
      SET_ACC(acc, 0.f, 0.f);
      staged_pass(As, Bs, p.whh1 + (size_t)cb * Hh, Hh, lm, q, wv, acc);
      TL(mb, colw, acc, {
        const short hv = f2bf(tanhf(z + bf2f(prs[n][r])));
        ST_BF16_PAIR(h1out, row, col, hv);
      });
    } else if (roleA == 1) {
      stage16(As, p.h2bf + (size_t)mb * Hh, tid);
      __syncthreads();
      SET_ACC(acc, bA0, bA1);
      staged_pass(As, Bs, p.whh2 + (size_t)cb * Hh, Hh, lm, q, wv, acc);
      TL(mb, colw, acc, { stf(p.acc2f + row * Hh + col, z); });
    } else if (roleA == 2) {
      if (t > 0) {
        float ex[2][4];
#pragma unroll
        for (int n = 0; n < 2; ++n)
#pragma unroll
          for (int r = 0; r < 4; ++r)
            ex[n][r] = ldf(p.ug1f + (mb + q * 4 + r) * Hh + colw + n * 16 + lm);
        stage16(As, p.h2bf + (size_t)mb * Hh, tid);
        __syncthreads();
        SET_ACC(acc, bA0, bA1);
        staged_pass(As, Bs, p.wg + Hh + (size_t)cb * (2 * Hh), 2 * Hh, lm, q, wv, acc);
        TL(mb, colw, acc, {
          const float s = z + ex[n][r];
          stf(p.uf + row * Hh + col, 1.0f / (1.0f + expf(-s)));
        });
      }
    } else {
      if (t > 0) {
        float ex[2][4];
        if (wv < 2) {
#pragma unroll
          for (int n = 0; n < 2; ++n)
#pragma unroll
            for (int r = 0; r < 4; ++r)
              ex[n][r] = ldf(p.o1f + (mb + q * 4 + r) * Oo + colw + n * 16 + lm);
        }
        stage16(As, p.h2bf + (size_t)mb * Hh, tid);
        __syncthreads();
        if (wv < 2) {
          SET_ACC(acc, bA0, bA1);
          lds_pass2(As, lm, q, p.wo2, Hh, colw, acc);
          TL(mb, colw, acc, {
            p.out[(size_t)row * (Tt * Oo) + (size_t)(t - 1) * Oo + col] =
                ex[n][r] + tanhf(z);
          });
        }
      }
    }
    ++gen;
    grid_barrier(p.flags, p.go, gen, bid, tid);
    // ---------------- Phase B ----------------
    if (roleB == 4) {
      float a2[2][4], uu[2][4], h2o[2][4];
#pragma unroll
      for (int n = 0; n < 2; ++n)
#pragma unroll
        for (int r = 0; r < 4; ++r) {
          const int idx = (mb + q * 4 + r) * Hh + colw + n * 16 + lm;
          a2[n][r]  = ldf(p.acc2f + idx);
          uu[n][r]  = ldf(p.uf + idx);
          h2o[n][r] = p.h2f[idx];        // block-local plain RW
        }
      stage16(As, h1out + (size_t)mb * Hh, tid);
      __syncthreads();
      SET_ACC(acc, 0.f, 0.f);
      staged_pass(As, Bs, p.wih2 + (size_t)cb * Hh, Hh, lm, q, wv, acc);
      TL(mb, colw, acc, {
        const int idx = row * Hh + col;
        const float hn = tanhf(z + a2[n][r]);
        const float nv = fmaf(uu[n][r], hn - h2o[n][r], h2o[n][r]);
        p.h2f[idx] = nv;
        const short hv = f2bf(nv);
        ST_BF16_PAIR(p.h2bf, row, col, hv);
      });
    } else if (roleB == 5) {
      stage16(As, h1out + (size_t)mb * Hh, tid);
      __syncthreads();
      SET_ACC(acc, 0.f, 0.f);
      staged_pass(As, Bs, p.wg + (size_t)cb * (2 * Hh), 2 * Hh, lm, q, wv, acc);
      TL(mb, colw, acc, { stf(p.ug1f + row * Hh + col, z); });
    } else if (roleB == 6) {
      stage16(As, h1out + (size_t)mb * Hh, tid);
      __syncthreads();
      if (wv < 2) {
        SET_ACC(acc, bB0, bB1);
        lds_pass2(As, lm, q, p.wo1, Hh, colw, acc);
        TL(mb, colw, acc, { stf(p.o1f + row * Oo + col, tanhf(z)); });
      }
    }
    ++gen;
    grid_barrier(p.flags, p.go, gen, bid, tid);
  }
  // tail: out rows for t = Tt-1
  if (roleA == 3) {
    float ex[2][4];
    if (wv < 2) {
#pragma unroll
      for (int n = 0; n < 2; ++n)
#pragma unroll
        for (int r = 0; r < 4; ++r)
          ex[n][r] = ldf(p.o1f + (mb + q * 4 + r) * Oo + colw + n * 16 + lm);
    }
    stage16(As, p.h2bf + (size_t)mb * Hh, tid);
    __syncthreads();
    if (wv < 2) {
      SET_ACC(acc, bA0, bA1);
      lds_pass2(As, lm, q, p.wo2, Hh, colw, acc);
      TL(mb, colw, acc, {
        p.out[(size_t)row * (Tt * Oo) + (size_t)(Tt - 1) * Oo + col] =
            ex[n][r] + tanhf(z);
      });
    }
  }
}

// pre_x[t][b][j] = x[b,t,:] @ W_ih1[j,:] + b_ih1[j] + b_hh1[j]  (stored bf16)
__global__ void __launch_bounds__(256) prex_kernel(
    const float* __restrict__ x, const float* __restrict__ wih1,
    const float* __restrict__ b_ih1, const float* __restrict__ b_hh1,
    short* __restrict__ prex) {
  const int tid = threadIdx.x;
  const int lane = tid & 63;
  const int wv = tid >> 6;
  const int lm = lane & 15;
  const int q = lane >> 4;
  const int bm = blockIdx.x >> 4;
  const int bn = blockIdx.x & 15;
  const int rowbase = bm * 64;
  const int col = bn * 64 + wv * 16 + lm;

  const f32x4 z4 = {0.f, 0.f, 0.f, 0.f};
  f32x4 acc[4];
#pragma unroll
  for (int mt = 0; mt < 4; ++mt) acc[mt] = z4;

#pragma unroll
  for (int kc = 0; kc < 2; ++kc) {
    const float* bp = wih1 + col * 64 + kc * 32 + q * 8;
    bf16x8 bf;
#pragma unroll
    for (int j = 0; j < 8; ++j) bf[j] = f2bf(bp[j]);
#pragma unroll
    for (int mt = 0; mt < 4; ++mt) {
      const float* ap = x + (size_t)(rowbase + mt * 16 + lm) * 64 + kc * 32 + q * 8;
      bf16x8 af;
#pragma unroll
      for (int j = 0; j < 8; ++j) af[j] = f2bf(ap[j]);
      acc[mt] = __builtin_amdgcn_mfma_f32_16x16x32_bf16(af, bf, acc[mt], 0, 0, 0);
    }
  }
  const float bia = b_ih1[col] + b_hh1[col];
#pragma unroll
  for (int mt = 0; mt < 4; ++mt) {
#pragma unroll
    for (int r = 0; r < 4; ++r) {
      const int row = rowbase + mt * 16 + q * 4 + r;  // row = b*256 + t
      const int b  = row >> 8;
      const int tt = row & 255;
      prex[((size_t)tt * Bb + b) * Hh + col] = f2bf(acc[mt][r] + bia);
    }
  }
}

__global__ void conv_kernel(const float* __restrict__ s, short* __restrict__ d, int n) {
  int i = blockIdx.x * blockDim.x + threadIdx.x;
  const int stride = gridDim.x * blockDim.x;
  for (; i < n; i += stride) d[i] = f2bf(s[i]);
}

__global__ void init_kernel(short* h1a, short* h1b, short* h2bf, float* h2f,
                            float* uf, unsigned* flags, unsigned* go) {
  const int i = blockIdx.x * blockDim.x + threadIdx.x;  // exactly 128*1024
  h1a[i] = 0; h1b[i] = 0; h2bf[i] = 0; h2f[i] = 0.f; uf[i] = 1.0f;
  if (i < 256) flags[i * FLAG_STRIDE] = (i < NBLK) ? 0u : 0xFFFFFFFFu;
  if (i == 0) *go = 0u;
}

extern "C" void kernel_launch(void* const* d_in, const int* in_sizes, int n_in,
                              void* d_out, int out_size, void* d_ws, size_t ws_size,
                              hipStream_t stream) {
  (void)in_sizes; (void)n_in; (void)out_size; (void)ws_size;
  const float* x      = (const float*)d_in[0];
  const float* W_ih1  = (const float*)d_in[1];
  const float* b_ih1  = (const float*)d_in[2];
  const float* W_hh1  = (const float*)d_in[3];
  const float* b_hh1  = (const float*)d_in[4];
  const float* W_ih2  = (const float*)d_in[5];
  const float* b_ih2  = (const float*)d_in[6];
  const float* W_hh2  = (const float*)d_in[7];
  const float* b_hh2  = (const float*)d_in[8];
  const float* Wg     = (const float*)d_in[9];
  const float* bg     = (const float*)d_in[10];
  const float* Wo1    = (const float*)d_in[11];
  const float* bo1    = (const float*)d_in[12];
  const float* Wo2    = (const float*)d_in[13];
  const float* bo2    = (const float*)d_in[14];

  char* ws = (char*)d_ws;
  size_t off = 0;
  auto alloc = [&](size_t bytes) -> void* {
    void* ptr = ws + off;
    off += (bytes + 255) & ~(size_t)255;
    return ptr;
  };
  short* whh1 = (short*)alloc((size_t)Hh * Hh * 2);
  short* wih2 = (short*)alloc((size_t)Hh * Hh * 2);
  short* whh2 = (short*)alloc((size_t)Hh * Hh * 2);
  short* wg   = (short*)alloc((size_t)Hh * 2 * Hh * 2);
  short* wo1  = (short*)alloc((size_t)Oo * Hh * 2);
  short* wo2  = (short*)alloc((size_t)Oo * Hh * 2);
  short* prex = (short*)alloc((size_t)Bb * Tt * Hh * 2);
  short* h1a  = (short*)alloc((size_t)Bb * Hh * 2);
  short* h1b  = (short*)alloc((size_t)Bb * Hh * 2);
  short* h2bf = (short*)alloc((size_t)Bb * Hh * 2);
  float* h2f  = (float*)alloc((size_t)Bb * Hh * 4);
  float* uf   = (float*)alloc((size_t)Bb * Hh * 4);
  float* ug1f = (float*)alloc((size_t)Bb * Hh * 4);
  float* acc2f= (float*)alloc((size_t)Bb * Hh * 4);
  float* o1f  = (float*)alloc((size_t)Bb * Oo * 4);
  unsigned* flags = (unsigned*)alloc(256 * FLAG_STRIDE * 4);   // 32 KB
  unsigned* go    = (unsigned*)alloc(256);

  conv_kernel<<<1024, 256, 0, stream>>>(W_hh1, whh1, Hh * Hh);
  conv_kernel<<<1024, 256, 0, stream>>>(W_ih2, wih2, Hh * Hh);
  conv_kernel<<<1024, 256, 0, stream>>>(W_hh2, whh2, Hh * Hh);
  conv_kernel<<<2048, 256, 0, stream>>>(Wg,    wg,   Hh * 2 * Hh);
  conv_kernel<<<256,  256, 0, stream>>>(Wo1,   wo1,  Oo * Hh);
  conv_kernel<<<256,  256, 0, stream>>>(Wo2,   wo2,  Oo * Hh);
  init_kernel<<<512, 256, 0, stream>>>(h1a, h1b, h2bf, h2f, uf, flags, go);
  prex_kernel<<<8192, 256, 0, stream>>>(x, W_ih1, b_ih1, b_hh1, prex);

  RP p;
  p.h1a = h1a; p.h1b = h1b; p.h2bf = h2bf;
  p.h2f = h2f; p.uf = uf; p.ug1f = ug1f; p.acc2f = acc2f; p.o1f = o1f;
  p.prex = prex;
  p.whh1 = whh1; p.wih2 = wih2; p.whh2 = whh2;
  p.wg = wg; p.wo1 = wo1; p.wo2 = wo2;
  p.b_ih2 = b_ih2; p.b_hh2 = b_hh2;
  p.bg = bg; p.bo1 = bo1; p.bo2 = bo2;
  p.out = (float*)d_out;
  p.flags = flags;
  p.go = go;

  rnn_kernel<<<NBLK, 256, 0, stream>>>(p);
}

// Round 2
// 3241.274 us; speedup vs baseline: 4.1042x; 4.1042x over previous
//
#include <hip/hip_runtime.h>
#include <cstddef>

using bf16x8 = __attribute__((ext_vector_type(8))) short;
using f32x4  = __attribute__((ext_vector_type(4))) float;

constexpr int Bb = 128;
constexpr int Tt = 256;
constexpr int Hh = 1024;
constexpr int Oo = 64;
constexpr int NBLK = 168;         // 32 H1 + 32 P2 + 32 PG + 4 PO + 64 H2U + 4 ZO
constexpr int FLAG_STRIDE = 32;   // dwords -> 128B between flags
constexpr int RS = 1048;          // LDS row stride in shorts (bank-spread, proven r0)

__device__ __forceinline__ float bf2f(short s) {
  unsigned int u = ((unsigned int)(unsigned short)s) << 16;
  float f;
  __builtin_memcpy(&f, &u, 4);
  return f;
}
__device__ __forceinline__ short f2bf(float f) {
  unsigned int u;
  __builtin_memcpy(&u, &f, 4);
  u += 0x7fffu + ((u >> 16) & 1u);  // round-to-nearest-even
  return (short)(u >> 16);
}
__device__ __forceinline__ bf16x8 as_bf(int4 v) {
  union { int4 i; bf16x8 b; } u; u.i = v; return u.b;
}
__device__ __forceinline__ float ldf(const float* p) {
  return __hip_atomic_load((float*)p, __ATOMIC_RELAXED, __HIP_MEMORY_SCOPE_AGENT);
}
__device__ __forceinline__ void stf(float* p, float v) {
  __hip_atomic_store(p, v, __ATOMIC_RELAXED, __HIP_MEMORY_SCOPE_AGENT);
}
__device__ __forceinline__ unsigned ldu(const unsigned* p) {
  return __hip_atomic_load((unsigned*)p, __ATOMIC_RELAXED, __HIP_MEMORY_SCOPE_AGENT);
}

// Agent-scope (sc1) coherent 16B load — LLC-coherent (cross-XCD state reads).
#define LD16A(d, p) asm volatile("global_load_dwordx4 %0, %1, off sc1" \
                                 : "=v"(d) : "v"((const void*)(p)))

// Stage one 32-row x 1024-col bf16 state slab into LDS.
// 256 threads x 16 sc1 loads (row = tid>>3, 8 threads/row), then LDS writes.
// Ends with vmcnt(0): no outstanding VMEM at pass entry.
__device__ __forceinline__ void stage32(short* As, const short* src, int tid) {
  const int row = tid >> 3;          // 0..31
  const int c0  = (tid & 7) * 8;     // shorts
  const short* gp = src + (size_t)row * Hh + c0;
  short* lp = As + row * RS + c0;
  int4 r0[8], r1[8];
#pragma unroll
  for (int j = 0; j < 8; ++j) LD16A(r0[j], gp + j * 64);
#pragma unroll
  for (int j = 0; j < 8; ++j) LD16A(r1[j], gp + 512 + j * 64);
  asm volatile("s_waitcnt vmcnt(8)" ::: "memory");
#pragma unroll
  for (int j = 0; j < 8; ++j) *(int4*)(lp + j * 64) = r0[j];
  asm volatile("s_waitcnt vmcnt(0)" ::: "memory");
#pragma unroll
  for (int j = 0; j < 8; ++j) *(int4*)(lp + 512 + j * 64) = r1[j];
}

// Wave pass: 32 rows (LDS, 2 row-frags) x 2 B-streams, K=1024.
// B from L2-resident weights via PLAIN cached loads, 3-deep pipeline per
// stream (r0's proven structure). acc[n][rf]: stream n, row-frag rf.
// For "two col-frags of one matrix": B1 = B0's col+16. For H2U: B0=whh2
// col c, B1=wg2 col c (two different matrices, same output columns).
__device__ __forceinline__ void pass32(const short* As, int lm, int q,
    const short* __restrict__ B0, size_t st0,
    const short* __restrict__ B1, size_t st1, f32x4 (&acc)[2][2]) {
  const short* ap0 = As + lm * RS + q * 8;
  const short* ap1 = ap0 + 16 * RS;
  const short* bp0 = B0 + (size_t)lm * st0 + q * 8;
  const short* bp1 = B1 + (size_t)lm * st1 + q * 8;
  int4 b0v[3], b1v[3];
  b0v[0] = *(const int4*)(bp0);      b1v[0] = *(const int4*)(bp1);
  b0v[1] = *(const int4*)(bp0 + 32); b1v[1] = *(const int4*)(bp1 + 32);
#pragma unroll
  for (int c = 0; c < 32; ++c) {
    if (c + 2 < 32) {
      b0v[(c + 2) % 3] = *(const int4*)(bp0 + (c + 2) * 32);
      b1v[(c + 2) % 3] = *(const int4*)(bp1 + (c + 2) * 32);
    }
    const bf16x8 a0 = as_bf(*(const int4*)(ap0 + c * 32));
    const bf16x8 a1 = as_bf(*(const int4*)(ap1 + c * 32));
    const bf16x8 b0 = as_bf(b0v[c % 3]);
    const bf16x8 b1 = as_bf(b1v[c % 3]);
    acc[0][0] = __builtin_amdgcn_mfma_f32_16x16x32_bf16(a0, b0, acc[0][0], 0, 0, 0);
    acc[0][1] = __builtin_amdgcn_mfma_f32_16x16x32_bf16(a1, b0, acc[0][1], 0, 0, 0);
    acc[1][0] = __builtin_amdgcn_mfma_f32_16x16x32_bf16(a0, b1, acc[1][0], 0, 0, 0);
    acc[1][1] = __builtin_amdgcn_mfma_f32_16x16x32_bf16(a1, b1, acc[1][1], 0, 0, 0);
  }
}

// Hierarchical RMW-free grid barrier; 168 blocks -> block0 polls 3 slots/lane
// (slots 168..191 preset to 0xFFFFFFFF = always passed).
__device__ __forceinline__ void grid_barrier(unsigned* flags, unsigned* go,
                                             unsigned gen, int bid, int tid) {
  __builtin_amdgcn_s_waitcnt(0);
  __syncthreads();
  if (tid == 0)
    __hip_atomic_store(flags + (size_t)bid * FLAG_STRIDE, gen,
                       __ATOMIC_RELAXED, __HIP_MEMORY_SCOPE_AGENT);
  if (bid == 0) {
    if (tid < 64) {
      const unsigned* f = flags + (size_t)tid * FLAG_STRIDE;
      for (;;) {
        const unsigned a = ldu(f);
        const unsigned b = ldu(f +  64 * FLAG_STRIDE);
        const unsigned c = ldu(f + 128 * FLAG_STRIDE);
        if (__all((a >= gen) && (b >= gen) && (c >= gen))) break;
        __builtin_amdgcn_s_sleep(2);
      }
      if (tid == 0)
        __hip_atomic_store(go, gen, __ATOMIC_RELAXED, __HIP_MEMORY_SCOPE_AGENT);
    }
  } else if (tid < 64) {
    while (ldu(go) < gen)
      __builtin_amdgcn_s_sleep(2);
  }
  __syncthreads();
  asm volatile("" ::: "memory");
}

#define ST_BF16_PAIR(BASE, ROW, COL, HV) do {                              \
    const int _ov = __shfl_xor((int)(unsigned short)(HV), 1, 64);          \
    if ((lm & 1) == 0) {                                                   \
      const unsigned _pk = (unsigned)(unsigned short)(HV) | ((unsigned)_ov << 16); \
      __hip_atomic_store((unsigned*)((BASE) + (size_t)(ROW) * Hh + (COL)), _pk, \
                         __ATOMIC_RELAXED, __HIP_MEMORY_SCOPE_AGENT);      \
    } } while (0)

struct RP {
  short *h1a, *h1b;                 // h1 bf16 double buffer
  short *h2a, *h2b;                 // h2 bf16 double buffer
  float *h2f;                       // h2 f32 master (block-local tiles)
  float *pre2f;                     // 2 slots: Wih2@h1(t)+b_ih2+b_hh2
  float *pg1f;                      // 3 slots: Wg1@h1(t)+bg
  float *po1f;                      // 3 slots: tanh(Wo1@h1(t)+bo1)
  const short* prex;
  const short *whh1, *wih2, *whh2, *wg, *wo1, *wo2;
  const float *b_ih2, *b_hh2, *bg, *bo1, *bo2;
  float* out;
  unsigned *flags, *go;
};

// 3-stage software pipeline, ONE grid barrier per phase (259 phases).
//   phase ph:  H1  computes h1(ph)                        [ph < Tt]
//              PRE computes pre2/preg1/preo1 for t=ph-1   [1 <= ph <= Tt]
//              H2U step s=ph-2: z2=Whh2@h2(s-1), zg=Wg2@h2(s-1); then
//                  u(s-1)=sig(preg1(s-1)+zg), h2(s)=blend  [2 <= ph <= Tt+1]
//              ZO  out(s-1) = preo1(s-1)+tanh(Wo2@h2(s-1)) [3 <= ph <= Tt+2]
// Block map (XCD = bid%8; weight-slab sharers land on one XCD):
//   0-31  H1  [32r x 128c]   32-63 P2   64-95 PG   96-99 PO [32r x 64c]
//   100-163 H2U [32r x 64c of BOTH z2 & zg]        164-167 ZO [32r x 64c]
__global__ void __launch_bounds__(256, 1) rnn_kernel(RP p) {
  __shared__ short As[32 * RS];     // 67072 B
  const int tid = threadIdx.x;
  const int lane = tid & 63;
  const int wv = tid >> 6;
  const int lm = lane & 15;
  const int q = lane >> 4;
  const int bid = blockIdx.x;

  int role, mb, cb;
  if      (bid < 32)  { role = 0; mb = (bid >> 3) * 32;         cb = (bid & 7) * 128; }
  else if (bid < 64)  { role = 1; mb = ((bid - 32) >> 3) * 32;  cb = ((bid - 32) & 7) * 128; }
  else if (bid < 96)  { role = 2; mb = ((bid - 64) >> 3) * 32;  cb = ((bid - 64) & 7) * 128; }
  else if (bid < 100) { role = 3; mb = (bid - 96) * 32;         cb = 0; }
  else if (bid < 164) { role = 4; mb = ((bid - 100) >> 4) * 32; cb = ((bid - 100) & 15) * 64; }
  else                { role = 5; mb = (bid - 164) * 32;        cb = 0; }

  int colw;
  if (role == 4) colw = cb + wv * 16;                 // 16 cols/wave, 2 streams
  else if (role == 3 || role == 5) colw = (wv & 1) * 32;  // 64-col heads
  else colw = cb + wv * 32;

  float bias0 = 0.f, bias1 = 0.f;
  if (role == 1) {
    bias0 = p.b_ih2[colw + lm] + p.b_hh2[colw + lm];
    bias1 = p.b_ih2[colw + 16 + lm] + p.b_hh2[colw + 16 + lm];
  } else if (role == 2) {
    bias0 = p.bg[colw + lm]; bias1 = p.bg[colw + 16 + lm];
  } else if (role == 3) {
    bias0 = p.bo1[colw + lm]; bias1 = p.bo1[colw + 16 + lm];
  } else if (role == 5) {
    bias0 = p.bo2[colw + lm]; bias1 = p.bo2[colw + 16 + lm];
  }

  const short* B0; const short* B1;
  size_t st0 = Hh, st1 = Hh;
  if      (role == 0) { B0 = p.whh1 + (size_t)colw * Hh; B1 = p.whh1 + (size_t)(colw + 16) * Hh; }
  else if (role == 1) { B0 = p.wih2 + (size_t)colw * Hh; B1 = p.wih2 + (size_t)(colw + 16) * Hh; }
  else if (role == 2) { B0 = p.wg + (size_t)colw * (2 * Hh); B1 = p.wg + (size_t)(colw + 16) * (2 * Hh); st0 = st1 = 2 * Hh; }
  else if (role == 3) { B0 = p.wo1 + (size_t)colw * Hh; B1 = p.wo1 + (size_t)(colw + 16) * Hh; }
  else if (role == 4) { B0 = p.whh2 + (size_t)colw * Hh; B1 = p.wg + Hh + (size_t)colw * (2 * Hh); st1 = 2 * Hh; }
  else                { B0 = p.wo2 + (size_t)colw * Hh; B1 = p.wo2 + (size_t)(colw + 16) * Hh; }

  const size_t HS = (size_t)Bb * Hh;
  const f32x4 z4 = {0.f, 0.f, 0.f, 0.f};
  unsigned gen = 0;

  for (int ph = 0; ph <= Tt + 2; ++ph) {
    const short* h1prev = (ph & 1) ? p.h1a : p.h1b;   // slot (ph-1)&1
    short*       h1out  = (ph & 1) ? p.h1b : p.h1a;   // slot ph&1
    const int s = ph - 2;                             // H2 step index
    const short* h2prev = (s & 1) ? p.h2a : p.h2b;    // slot (s-1)&1
    short*       h2out  = (s & 1) ? p.h2b : p.h2a;    // slot s&1

    if (role == 0) {                       // ---- H1 chain: h1(ph) ----
      if (ph < Tt) {
        short prs[2][2][4];
        const short* pr = p.prex + (size_t)ph * HS;
#pragma unroll
        for (int n = 0; n < 2; ++n)
#pragma unroll
          for (int rf = 0; rf < 2; ++rf)
#pragma unroll
            for (int r = 0; r < 4; ++r)
              prs[n][rf][r] = pr[(size_t)(mb + rf * 16 + q * 4 + r) * Hh + colw + n * 16 + lm];
        stage32(As, h1prev + (size_t)mb * Hh, tid);
        __syncthreads();
        f32x4 acc[2][2]; acc[0][0] = acc[0][1] = acc[1][0] = acc[1][1] = z4;
        pass32(As, lm, q, B0, st0, B1, st1, acc);
#pragma unroll
        for (int n = 0; n < 2; ++n)
#pragma unroll
          for (int rf = 0; rf < 2; ++rf)
#pragma unroll
            for (int r = 0; r < 4; ++r) {
              const int row = mb + rf * 16 + q * 4 + r;
              const int col = colw + n * 16 + lm;
              const short hv = f2bf(tanhf(acc[n][rf][r] + bf2f(prs[n][rf][r])));
              ST_BF16_PAIR(h1out, row, col, hv);
            }
      }
    } else if (role == 1) {                // ---- pre2(t=ph-1) ----
      if (ph >= 1 && ph <= Tt) {
        float* dst = p.pre2f + (size_t)((ph - 1) & 1) * HS;
        stage32(As, h1prev + (size_t)mb * Hh, tid);
        __syncthreads();
        f32x4 acc[2][2]; acc[0][0] = acc[0][1] = acc[1][0] = acc[1][1] = z4;
        pass32(As, lm, q, B0, st0, B1, st1, acc);
#pragma unroll
        for (int n = 0; n < 2; ++n)
#pragma unroll
          for (int rf = 0; rf < 2; ++rf)
#pragma unroll
            for (int r = 0; r < 4; ++r) {
              const int row = mb + rf * 16 + q * 4 + r;
              const int col = colw + n * 16 + lm;
              stf(dst + (size_t)row * Hh + col, acc[n][rf][r] + (n ? bias1 : bias0));
            }
      }
    } else if (role == 2) {                // ---- preg1(t=ph-1) ----
      if (ph >= 1 && ph <= Tt) {
        float* dst = p.pg1f + (size_t)((ph - 1) % 3) * HS;
        stage32(As, h1prev + (size_t)mb * Hh, tid);
        __syncthreads();
        f32x4 acc[2][2]; acc[0][0] = acc[0][1] = acc[1][0] = acc[1][1] = z4;
        pass32(As, lm, q, B0, st0, B1, st1, acc);
#pragma unroll
        for (int n = 0; n < 2; ++n)
#pragma unroll
          for (int rf = 0; rf < 2; ++rf)
#pragma unroll
            for (int r = 0; r < 4; ++r) {
              const int row = mb + rf * 16 + q * 4 + r;
              const int col = colw + n * 16 + lm;
              stf(dst + (size_t)row * Hh + col, acc[n][rf][r] + (n ? bias1 : bias0));
            }
      }
    } else if (role == 3) {                // ---- preo1(t=ph-1) ----
      if (ph >= 1 && ph <= Tt) {
        float* dst = p.po1f + (size_t)((ph - 1) % 3) * (Bb * Oo);
        stage32(As, h1prev + (size_t)mb * Hh, tid);
        __syncthreads();
        if (wv < 2) {
          f32x4 acc[2][2]; acc[0][0] = acc[0][1] = acc[1][0] = acc[1][1] = z4;
          pass32(As, lm, q, B0, st0, B1, st1, acc);
#pragma unroll
          for (int n = 0; n < 2; ++n)
#pragma unroll
            for (int rf = 0; rf < 2; ++rf)
#pragma unroll
              for (int r = 0; r < 4; ++r) {
                const int row = mb + rf * 16 + q * 4 + r;
                const int col = colw + n * 16 + lm;
                stf(dst + (size_t)row * Oo + col,
                    tanhf(acc[n][rf][r] + (n ? bias1 : bias0)));
              }
        }
      }
    } else if (role == 4) {                // ---- H2 step s ----
      if (ph >= 2 && ph <= Tt + 1) {
        float p2v[2][4], pg1v[2][4], hpv[2][4];
        const float* pre2s = p.pre2f + (size_t)(s & 1) * HS;
        const float* pg1s  = p.pg1f + (size_t)((s + 2) % 3) * HS;
#pragma unroll
        for (int rf = 0; rf < 2; ++rf)
#pragma unroll
          for (int r = 0; r < 4; ++r) {
            const size_t idx = (size_t)(mb + rf * 16 + q * 4 + r) * Hh + colw + lm;
            p2v[rf][r] = ldf(pre2s + idx);
            pg1v[rf][r] = (s > 0) ? ldf(pg1s + idx) : 0.f;
            hpv[rf][r] = p.h2f[idx];       // block-local plain RW
          }
        stage32(As, h2prev + (size_t)mb * Hh, tid);
        __syncthreads();
        f32x4 acc[2][2]; acc[0][0] = acc[0][1] = acc[1][0] = acc[1][1] = z4;
        pass32(As, lm, q, B0, st0, B1, st1, acc);   // acc[0]=z2, acc[1]=zg
#pragma unroll
        for (int rf = 0; rf < 2; ++rf)
#pragma unroll
          for (int r = 0; r < 4; ++r) {
            const int row = mb + rf * 16 + q * 4 + r;
            const int col = colw + lm;
            const size_t idx = (size_t)row * Hh + col;
            const float u = (s == 0) ? 1.f
                : 1.f / (1.f + expf(-(acc[1][rf][r] + pg1v[rf][r])));
            const float hn = tanhf(acc[0][rf][r] + p2v[rf][r]);
            const float nv = fmaf(u, hn - hpv[rf][r], hpv[rf][r]);
            p.h2f[idx] = nv;
            const short hv = f2bf(nv);
            ST_BF16_PAIR(h2out, row, col, hv);
          }
      }
    } else {                               // ---- out(s-1) ----
      if (ph >= 3) {
        const int to = ph - 3;
        const float* po1s = p.po1f + (size_t)(to % 3) * (Bb * Oo);
        float pv[2][2][4];
        if (wv < 2) {
#pragma unroll
          for (int n = 0; n < 2; ++n)
#pragma unroll
            for (int rf = 0; rf < 2; ++rf)
#pragma unroll
              for (int r = 0; r < 4; ++r)
                pv[n][rf][r] = ldf(po1s + (size_t)(mb + rf * 16 + q * 4 + r) * Oo
                                   + colw + n * 16 + lm);
        }
        stage32(As, h2prev + (size_t)mb * Hh, tid);
        __syncthreads();
        if (wv < 2) {
          f32x4 acc[2][2]; acc[0][0] = acc[0][1] = acc[1][0] = acc[1][1] = z4;
          pass32(As, lm, q, B0, st0, B1, st1, acc);
#pragma unroll
          for (int n = 0; n < 2; ++n)
#pragma unroll
            for (int rf = 0; rf < 2; ++rf)
#pragma unroll
              for (int r = 0; r < 4; ++r) {
                const int row = mb + rf * 16 + q * 4 + r;
                const int col = colw + n * 16 + lm;
                p.out[(size_t)row * (Tt * Oo) + (size_t)to * Oo + col] =
                    pv[n][rf][r] + tanhf(acc[n][rf][r] + (n ? bias1 : bias0));
              }
        }
      }
    }
    ++gen;
    grid_barrier(p.flags, p.go, gen, bid, tid);
  }
}

// pre_x[t][b][j] = x[b,t,:] @ W_ih1[j,:] + b_ih1[j] + b_hh1[j]  (stored bf16)
__global__ void __launch_bounds__(256) prex_kernel(
    const float* __restrict__ x, const float* __restrict__ wih1,
    const float* __restrict__ b_ih1, const float* __restrict__ b_hh1,
    short* __restrict__ prex) {
  const int tid = threadIdx.x;
  const int lane = tid & 63;
  const int wv = tid >> 6;
  const int lm = lane & 15;
  const int q = lane >> 4;
  const int bm = blockIdx.x >> 4;
  const int bn = blockIdx.x & 15;
  const int rowbase = bm * 64;
  const int col = bn * 64 + wv * 16 + lm;

  const f32x4 z4 = {0.f, 0.f, 0.f, 0.f};
  f32x4 acc[4];
#pragma unroll
  for (int mt = 0; mt < 4; ++mt) acc[mt] = z4;

#pragma unroll
  for (int kc = 0; kc < 2; ++kc) {
    const float* bp = wih1 + col * 64 + kc * 32 + q * 8;
    bf16x8 bf;
#pragma unroll
    for (int j = 0; j < 8; ++j) bf[j] = f2bf(bp[j]);
#pragma unroll
    for (int mt = 0; mt < 4; ++mt) {
      const float* ap = x + (size_t)(rowbase + mt * 16 + lm) * 64 + kc * 32 + q * 8;
      bf16x8 af;
#pragma unroll
      for (int j = 0; j < 8; ++j) af[j] = f2bf(ap[j]);
      acc[mt] = __builtin_amdgcn_mfma_f32_16x16x32_bf16(af, bf, acc[mt], 0, 0, 0);
    }
  }
  const float bia = b_ih1[col] + b_hh1[col];
#pragma unroll
  for (int mt = 0; mt < 4; ++mt) {
#pragma unroll
    for (int r = 0; r < 4; ++r) {
      const int row = rowbase + mt * 16 + q * 4 + r;  // row = b*256 + t
      const int b  = row >> 8;
      const int tt = row & 255;
      prex[((size_t)tt * Bb + b) * Hh + col] = f2bf(acc[mt][r] + bia);
    }
  }
}

__global__ void conv_kernel(const float* __restrict__ s, short* __restrict__ d, int n) {
  int i = blockIdx.x * blockDim.x + threadIdx.x;
  const int stride = gridDim.x * blockDim.x;
  for (; i < n; i += stride) d[i] = f2bf(s[i]);
}

__global__ void init_kernel(short* h1a, short* h1b, short* h2a, short* h2b,
                            float* h2f, unsigned* flags, unsigned* go) {
  const int i = blockIdx.x * blockDim.x + threadIdx.x;  // exactly 128*1024
  h1a[i] = 0; h1b[i] = 0; h2a[i] = 0; h2b[i] = 0; h2f[i] = 0.f;
  if (i < 256) flags[i * FLAG_STRIDE] = (i < NBLK) ? 0u : 0xFFFFFFFFu;
  if (i == 0) *go = 0u;
}

extern "C" void kernel_launch(void* const* d_in, const int* in_sizes, int n_in,
                              void* d_out, int out_size, void* d_ws, size_t ws_size,
                              hipStream_t stream) {
  (void)in_sizes; (void)n_in; (void)out_size; (void)ws_size;
  const float* x      = (const float*)d_in[0];
  const float* W_ih1  = (const float*)d_in[1];
  const float* b_ih1  = (const float*)d_in[2];
  const float* W_hh1  = (const float*)d_in[3];
  const float* b_hh1  = (const float*)d_in[4];
  const float* W_ih2  = (const float*)d_in[5];
  const float* b_ih2  = (const float*)d_in[6];
  const float* W_hh2  = (const float*)d_in[7];
  const float* b_hh2  = (const float*)d_in[8];
  const float* Wg     = (const float*)d_in[9];
  const float* bg     = (const float*)d_in[10];
  const float* Wo1    = (const float*)d_in[11];
  const float* bo1    = (const float*)d_in[12];
  const float* Wo2    = (const float*)d_in[13];
  const float* bo2    = (const float*)d_in[14];

  char* ws = (char*)d_ws;
  size_t off = 0;
  auto alloc = [&](size_t bytes) -> void* {
    void* ptr = ws + off;
    off += (bytes + 255) & ~(size_t)255;
    return ptr;
  };
  short* whh1 = (short*)alloc((size_t)Hh * Hh * 2);
  short* wih2 = (short*)alloc((size_t)Hh * Hh * 2);
  short* whh2 = (short*)alloc((size_t)Hh * Hh * 2);
  short* wg   = (short*)alloc((size_t)Hh * 2 * Hh * 2);
  short* wo1  = (short*)alloc((size_t)Oo * Hh * 2);
  short* wo2  = (short*)alloc((size_t)Oo * Hh * 2);
  short* prex = (short*)alloc((size_t)Bb * Tt * Hh * 2);
  short* h1a  = (short*)alloc((size_t)Bb * Hh * 2);
  short* h1b  = (short*)alloc((size_t)Bb * Hh * 2);
  short* h2a  = (short*)alloc((size_t)Bb * Hh * 2);
  short* h2b  = (short*)alloc((size_t)Bb * Hh * 2);
  float* h2f  = (float*)alloc((size_t)Bb * Hh * 4);
  float* pre2f= (float*)alloc((size_t)2 * Bb * Hh * 4);
  float* pg1f = (float*)alloc((size_t)3 * Bb * Hh * 4);
  float* po1f = (float*)alloc((size_t)3 * Bb * Oo * 4);
  unsigned* flags = (unsigned*)alloc(256 * FLAG_STRIDE * 4);   // 32 KB
  unsigned* go    = (unsigned*)alloc(256);

  conv_kernel<<<1024, 256, 0, stream>>>(W_hh1, whh1, Hh * Hh);
  conv_kernel<<<1024, 256, 0, stream>>>(W_ih2, wih2, Hh * Hh);
  conv_kernel<<<1024, 256, 0, stream>>>(W_hh2, whh2, Hh * Hh);
  conv_kernel<<<2048, 256, 0, stream>>>(Wg,    wg,   Hh * 2 * Hh);
  conv_kernel<<<256,  256, 0, stream>>>(Wo1,   wo1,  Oo * Hh);
  conv_kernel<<<256,  256, 0, stream>>>(Wo2,   wo2,  Oo * Hh);
  init_kernel<<<512, 256, 0, stream>>>(h1a, h1b, h2a, h2b, h2f, flags, go);
  prex_kernel<<<8192, 256, 0, stream>>>(x, W_ih1, b_ih1, b_hh1, prex);

  RP p;
  p.h1a = h1a; p.h1b = h1b; p.h2a = h2a; p.h2b = h2b;
  p.h2f = h2f; p.pre2f = pre2f; p.pg1f = pg1f; p.po1f = po1f;
  p.prex = prex;
  p.whh1 = whh1; p.wih2 = wih2; p.whh2 = whh2;
  p.wg = wg; p.wo1 = wo1; p.wo2 = wo2;
  p.b_ih2 = b_ih2; p.b_hh2 = b_hh2;
  p.bg = bg; p.bo1 = bo1; p.bo2 = bo2;
  p.out = (float*)d_out;
  p.flags = flags;
  p.go = go;

  rnn_kernel<<<NBLK, 256, 0, stream>>>(p);
}

// Round 3
// 3234.410 us; speedup vs baseline: 4.1129x; 1.0021x over previous
//
#include <hip/hip_runtime.h>
#include <cstddef>

using bf16x8 = __attribute__((ext_vector_type(8))) short;
using f32x4  = __attribute__((ext_vector_type(4))) float;

constexpr int Bb = 128;
constexpr int Tt = 256;
constexpr int Hh = 1024;
constexpr int Oo = 64;
constexpr int NBLK = 168;         // 32 H1 + 32 P2 + 32 PG + 4 PO + 64 H2U + 4 ZO
constexpr int FLAG_STRIDE = 32;   // dwords -> 128B between flags
constexpr int RS = 1048;          // LDS row stride in shorts (bank-spread, proven r0)

__device__ __forceinline__ float bf2f(short s) {
  unsigned int u = ((unsigned int)(unsigned short)s) << 16;
  float f;
  __builtin_memcpy(&f, &u, 4);
  return f;
}
__device__ __forceinline__ short f2bf(float f) {
  unsigned int u;
  __builtin_memcpy(&u, &f, 4);
  u += 0x7fffu + ((u >> 16) & 1u);  // round-to-nearest-even
  return (short)(u >> 16);
}
__device__ __forceinline__ bf16x8 as_bf(int4 v) {
  union { int4 i; bf16x8 b; } u; u.i = v; return u.b;
}
__device__ __forceinline__ float ldf(const float* p) {
  return __hip_atomic_load((float*)p, __ATOMIC_RELAXED, __HIP_MEMORY_SCOPE_AGENT);
}
__device__ __forceinline__ void stf(float* p, float v) {
  __hip_atomic_store(p, v, __ATOMIC_RELAXED, __HIP_MEMORY_SCOPE_AGENT);
}
__device__ __forceinline__ unsigned ldu(const unsigned* p) {
  return __hip_atomic_load((unsigned*)p, __ATOMIC_RELAXED, __HIP_MEMORY_SCOPE_AGENT);
}

// Agent-scope (sc1) coherent 16B load — LLC-coherent (cross-XCD state reads).
#define LD16A(d, p) asm volatile("global_load_dwordx4 %0, %1, off sc1" \
                                 : "=v"(d) : "v"((const void*)(p)))

// Stage one 32-row x 1024-col bf16 state slab into LDS.
// 256 threads x 16 sc1 loads (row = tid>>3, 8 threads/row), then LDS writes.
// NOTE: counted waits are conservative-valid even with earlier (B-prefill /
// epilogue) loads still outstanding: vmcnt(N) waits for all-but-N oldest,
// which always covers the state loads needed for each LDS write half.
__device__ __forceinline__ void stage32(short* As, const short* src, int tid) {
  const int row = tid >> 3;          // 0..31
  const int c0  = (tid & 7) * 8;     // shorts
  const short* gp = src + (size_t)row * Hh + c0;
  short* lp = As + row * RS + c0;
  int4 r0[8], r1[8];
#pragma unroll
  for (int j = 0; j < 8; ++j) LD16A(r0[j], gp + j * 64);
#pragma unroll
  for (int j = 0; j < 8; ++j) LD16A(r1[j], gp + 512 + j * 64);
  asm volatile("s_waitcnt vmcnt(8)" ::: "memory");
#pragma unroll
  for (int j = 0; j < 8; ++j) *(int4*)(lp + j * 64) = r0[j];
  asm volatile("s_waitcnt vmcnt(0)" ::: "memory");
#pragma unroll
  for (int j = 0; j < 8; ++j) *(int4*)(lp + 512 + j * 64) = r1[j];
}

// 6-deep B-ring, split into prefill (issued BEFORE the state stage + sync,
// so the first ~5 iterations' L2 latency hides under the LLC state wait)
// and the MFMA pass (slack 5 iters ~ 300cy > L2 latency -> issue-bound).
struct BPre {
  const short *bp0, *bp1;
  int4 b0v[6], b1v[6];
};
__device__ __forceinline__ void prefillB(BPre& P,
    const short* __restrict__ B0, size_t st0,
    const short* __restrict__ B1, size_t st1, int lm, int q) {
  P.bp0 = B0 + (size_t)lm * st0 + q * 8;
  P.bp1 = B1 + (size_t)lm * st1 + q * 8;
#pragma unroll
  for (int c = 0; c < 5; ++c) {
    P.b0v[c] = *(const int4*)(P.bp0 + c * 32);
    P.b1v[c] = *(const int4*)(P.bp1 + c * 32);
  }
}
// Wave pass: 32 rows (LDS, 2 row-frags) x 2 B-streams, K=1024.
// acc[n][rf]: stream n, row-frag rf. All ring indices are compile-time
// (full unroll) -> registers, no scratch (rule #20).
__device__ __forceinline__ void pass32p(const short* As, int lm, int q,
    BPre& P, f32x4 (&acc)[2][2]) {
  const short* ap0 = As + lm * RS + q * 8;
  const short* ap1 = ap0 + 16 * RS;
#pragma unroll
  for (int c = 0; c < 32; ++c) {
    if (c + 5 < 32) {
      P.b0v[(c + 5) % 6] = *(const int4*)(P.bp0 + (c + 5) * 32);
      P.b1v[(c + 5) % 6] = *(const int4*)(P.bp1 + (c + 5) * 32);
    }
    const bf16x8 a0 = as_bf(*(const int4*)(ap0 + c * 32));
    const bf16x8 a1 = as_bf(*(const int4*)(ap1 + c * 32));
    const bf16x8 b0 = as_bf(P.b0v[c % 6]);
    const bf16x8 b1 = as_bf(P.b1v[c % 6]);
    acc[0][0] = __builtin_amdgcn_mfma_f32_16x16x32_bf16(a0, b0, acc[0][0], 0, 0, 0);
    acc[0][1] = __builtin_amdgcn_mfma_f32_16x16x32_bf16(a1, b0, acc[0][1], 0, 0, 0);
    acc[1][0] = __builtin_amdgcn_mfma_f32_16x16x32_bf16(a0, b1, acc[1][0], 0, 0, 0);
    acc[1][1] = __builtin_amdgcn_mfma_f32_16x16x32_bf16(a1, b1, acc[1][1], 0, 0, 0);
  }
}

// FLAT RMW-free grid barrier: every block polls all 192 slots itself
// (slots 168..191 preset to 0xFFFFFFFF). One LLC propagation instead of
// the previous two-hop flags -> block0 -> go.
__device__ __forceinline__ void grid_barrier(unsigned* flags,
                                             unsigned gen, int bid, int tid) {
  __builtin_amdgcn_s_waitcnt(0);
  __syncthreads();
  if (tid == 0)
    __hip_atomic_store(flags + (size_t)bid * FLAG_STRIDE, gen,
                       __ATOMIC_RELAXED, __HIP_MEMORY_SCOPE_AGENT);
  if (tid < 64) {
    const unsigned* f = flags + (size_t)tid * FLAG_STRIDE;
    for (;;) {
      const unsigned a = ldu(f);
      const unsigned b = ldu(f +  64 * FLAG_STRIDE);
      const unsigned c = ldu(f + 128 * FLAG_STRIDE);
      if (__all((a >= gen) && (b >= gen) && (c >= gen))) break;
      __builtin_amdgcn_s_sleep(1);
    }
  }
  __syncthreads();
  asm volatile("" ::: "memory");
}

#define ST_BF16_PAIR(BASE, ROW, COL, HV) do {                              \
    const int _ov = __shfl_xor((int)(unsigned short)(HV), 1, 64);          \
    if ((lm & 1) == 0) {                                                   \
      const unsigned _pk = (unsigned)(unsigned short)(HV) | ((unsigned)_ov << 16); \
      __hip_atomic_store((unsigned*)((BASE) + (size_t)(ROW) * Hh + (COL)), _pk, \
                         __ATOMIC_RELAXED, __HIP_MEMORY_SCOPE_AGENT);      \
    } } while (0)

struct RP {
  short *h1a, *h1b;                 // h1 bf16 double buffer
  short *h2a, *h2b;                 // h2 bf16 double buffer
  float *h2f;                       // h2 f32 master (block-local tiles)
  float *pre2f;                     // 2 slots: Wih2@h1(t)+b_ih2+b_hh2
  float *pg1f;                      // 3 slots: Wg1@h1(t)+bg
  float *po1f;                      // 3 slots: tanh(Wo1@h1(t)+bo1)
  const short* prex;
  const short *whh1, *wih2, *whh2, *wg, *wo1, *wo2;
  const float *b_ih2, *b_hh2, *bg, *bo1, *bo2;
  float* out;
  unsigned *flags;
};

// 3-stage software pipeline, ONE grid barrier per phase (259 phases).
//   phase ph:  H1  computes h1(ph)                        [ph < Tt]
//              PRE computes pre2/preg1/preo1 for t=ph-1   [1 <= ph <= Tt]
//              H2U step s=ph-2: z2=Whh2@h2(s-1), zg=Wg2@h2(s-1); then
//                  u(s-1)=sig(preg1(s-1)+zg), h2(s)=blend  [2 <= ph <= Tt+1]
//              ZO  out(s-1) = preo1(s-1)+tanh(Wo2@h2(s-1)) [3 <= ph <= Tt+2]
// Block map (XCD = bid%8; weight-slab sharers land on one XCD):
//   0-31  H1  [32r x 128c]   32-63 P2   64-95 PG   96-99 PO [32r x 64c]
//   100-163 H2U [32r x 64c of BOTH z2 & zg]        164-167 ZO [32r x 64c]
__global__ void __launch_bounds__(256, 1) rnn_kernel(RP p) {
  __shared__ short As[32 * RS];     // 67072 B
  const int tid = threadIdx.x;
  const int lane = tid & 63;
  const int wv = tid >> 6;
  const int lm = lane & 15;
  const int q = lane >> 4;
  const int bid = blockIdx.x;

  int role, mb, cb;
  if      (bid < 32)  { role = 0; mb = (bid >> 3) * 32;         cb = (bid & 7) * 128; }
  else if (bid < 64)  { role = 1; mb = ((bid - 32) >> 3) * 32;  cb = ((bid - 32) & 7) * 128; }
  else if (bid < 96)  { role = 2; mb = ((bid - 64) >> 3) * 32;  cb = ((bid - 64) & 7) * 128; }
  else if (bid < 100) { role = 3; mb = (bid - 96) * 32;         cb = 0; }
  else if (bid < 164) { role = 4; mb = ((bid - 100) >> 4) * 32; cb = ((bid - 100) & 15) * 64; }
  else                { role = 5; mb = (bid - 164) * 32;        cb = 0; }

  int colw;
  if (role == 4) colw = cb + wv * 16;                 // 16 cols/wave, 2 streams
  else if (role == 3 || role == 5) colw = (wv & 1) * 32;  // 64-col heads
  else colw = cb + wv * 32;

  float bias0 = 0.f, bias1 = 0.f;
  if (role == 1) {
    bias0 = p.b_ih2[colw + lm] + p.b_hh2[colw + lm];
    bias1 = p.b_ih2[colw + 16 + lm] + p.b_hh2[colw + 16 + lm];
  } else if (role == 2) {
    bias0 = p.bg[colw + lm]; bias1 = p.bg[colw + 16 + lm];
  } else if (role == 3) {
    bias0 = p.bo1[colw + lm]; bias1 = p.bo1[colw + 16 + lm];
  } else if (role == 5) {
    bias0 = p.bo2[colw + lm]; bias1 = p.bo2[colw + 16 + lm];
  }

  const short* B0; const short* B1;
  size_t st0 = Hh, st1 = Hh;
  if      (role == 0) { B0 = p.whh1 + (size_t)colw * Hh; B1 = p.whh1 + (size_t)(colw + 16) * Hh; }
  else if (role == 1) { B0 = p.wih2 + (size_t)colw * Hh; B1 = p.wih2 + (size_t)(colw + 16) * Hh; }
  else if (role == 2) { B0 = p.wg + (size_t)colw * (2 * Hh); B1 = p.wg + (size_t)(colw + 16) * (2 * Hh); st0 = st1 = 2 * Hh; }
  else if (role == 3) { B0 = p.wo1 + (size_t)colw * Hh; B1 = p.wo1 + (size_t)(colw + 16) * Hh; }
  else if (role == 4) { B0 = p.whh2 + (size_t)colw * Hh; B1 = p.wg + Hh + (size_t)colw * (2 * Hh); st1 = 2 * Hh; }
  else                { B0 = p.wo2 + (size_t)colw * Hh; B1 = p.wo2 + (size_t)(colw + 16) * Hh; }

  const size_t HS = (size_t)Bb * Hh;
  const f32x4 z4 = {0.f, 0.f, 0.f, 0.f};
  unsigned gen = 0;

  for (int ph = 0; ph <= Tt + 2; ++ph) {
    const short* h1prev = (ph & 1) ? p.h1a : p.h1b;   // slot (ph-1)&1
    short*       h1out  = (ph & 1) ? p.h1b : p.h1a;   // slot ph&1
    const int s = ph - 2;                             // H2 step index
    const short* h2prev = (s & 1) ? p.h2a : p.h2b;    // slot (s-1)&1
    short*       h2out  = (s & 1) ? p.h2b : p.h2a;    // slot s&1

    if (role == 0) {                       // ---- H1 chain: h1(ph) ----
      if (ph < Tt) {
        BPre P; prefillB(P, B0, st0, B1, st1, lm, q);
        short prs[2][2][4];
        const short* pr = p.prex + (size_t)ph * HS;
#pragma unroll
        for (int n = 0; n < 2; ++n)
#pragma unroll
          for (int rf = 0; rf < 2; ++rf)
#pragma unroll
            for (int r = 0; r < 4; ++r)
              prs[n][rf][r] = pr[(size_t)(mb + rf * 16 + q * 4 + r) * Hh + colw + n * 16 + lm];
        stage32(As, h1prev + (size_t)mb * Hh, tid);
        __syncthreads();
        f32x4 acc[2][2]; acc[0][0] = acc[0][1] = acc[1][0] = acc[1][1] = z4;
        pass32p(As, lm, q, P, acc);
#pragma unroll
        for (int n = 0; n < 2; ++n)
#pragma unroll
          for (int rf = 0; rf < 2; ++rf)
#pragma unroll
            for (int r = 0; r < 4; ++r) {
              const int row = mb + rf * 16 + q * 4 + r;
              const int col = colw + n * 16 + lm;
              const short hv = f2bf(tanhf(acc[n][rf][r] + bf2f(prs[n][rf][r])));
              ST_BF16_PAIR(h1out, row, col, hv);
            }
      }
    } else if (role == 1) {                // ---- pre2(t=ph-1) ----
      if (ph >= 1 && ph <= Tt) {
        BPre P; prefillB(P, B0, st0, B1, st1, lm, q);
        float* dst = p.pre2f + (size_t)((ph - 1) & 1) * HS;
        stage32(As, h1prev + (size_t)mb * Hh, tid);
        __syncthreads();
        f32x4 acc[2][2]; acc[0][0] = acc[0][1] = acc[1][0] = acc[1][1] = z4;
        pass32p(As, lm, q, P, acc);
#pragma unroll
        for (int n = 0; n < 2; ++n)
#pragma unroll
          for (int rf = 0; rf < 2; ++rf)
#pragma unroll
            for (int r = 0; r < 4; ++r) {
              const int row = mb + rf * 16 + q * 4 + r;
              const int col = colw + n * 16 + lm;
              stf(dst + (size_t)row * Hh + col, acc[n][rf][r] + (n ? bias1 : bias0));
            }
      }
    } else if (role == 2) {                // ---- preg1(t=ph-1) ----
      if (ph >= 1 && ph <= Tt) {
        BPre P; prefillB(P, B0, st0, B1, st1, lm, q);
        float* dst = p.pg1f + (size_t)((ph - 1) % 3) * HS;
        stage32(As, h1prev + (size_t)mb * Hh, tid);
        __syncthreads();
        f32x4 acc[2][2]; acc[0][0] = acc[0][1] = acc[1][0] = acc[1][1] = z4;
        pass32p(As, lm, q, P, acc);
#pragma unroll
        for (int n = 0; n < 2; ++n)
#pragma unroll
          for (int rf = 0; rf < 2; ++rf)
#pragma unroll
            for (int r = 0; r < 4; ++r) {
              const int row = mb + rf * 16 + q * 4 + r;
              const int col = colw + n * 16 + lm;
              stf(dst + (size_t)row * Hh + col, acc[n][rf][r] + (n ? bias1 : bias0));
            }
      }
    } else if (role == 3) {                // ---- preo1(t=ph-1) ----
      if (ph >= 1 && ph <= Tt) {
        BPre P;
        if (wv < 2) prefillB(P, B0, st0, B1, st1, lm, q);
        float* dst = p.po1f + (size_t)((ph - 1) % 3) * (Bb * Oo);
        stage32(As, h1prev + (size_t)mb * Hh, tid);
        __syncthreads();
        if (wv < 2) {
          f32x4 acc[2][2]; acc[0][0] = acc[0][1] = acc[1][0] = acc[1][1] = z4;
          pass32p(As, lm, q, P, acc);
#pragma unroll
          for (int n = 0; n < 2; ++n)
#pragma unroll
            for (int rf = 0; rf < 2; ++rf)
#pragma unroll
              for (int r = 0; r < 4; ++r) {
                const int row = mb + rf * 16 + q * 4 + r;
                const int col = colw + n * 16 + lm;
                stf(dst + (size_t)row * Oo + col,
                    tanhf(acc[n][rf][r] + (n ? bias1 : bias0)));
              }
        }
      }
    } else if (role == 4) {                // ---- H2 step s ----
      if (ph >= 2 && ph <= Tt + 1) {
        BPre P; prefillB(P, B0, st0, B1, st1, lm, q);
        float p2v[2][4], pg1v[2][4], hpv[2][4];
        const float* pre2s = p.pre2f + (size_t)(s & 1) * HS;
        const float* pg1s  = p.pg1f + (size_t)((s + 2) % 3) * HS;
#pragma unroll
        for (int rf = 0; rf < 2; ++rf)
#pragma unroll
          for (int r = 0; r < 4; ++r) {
            const size_t idx = (size_t)(mb + rf * 16 + q * 4 + r) * Hh + colw + lm;
            p2v[rf][r] = ldf(pre2s + idx);
            pg1v[rf][r] = (s > 0) ? ldf(pg1s + idx) : 0.f;
            hpv[rf][r] = p.h2f[idx];       // block-local plain RW
          }
        stage32(As, h2prev + (size_t)mb * Hh, tid);
        __syncthreads();
        f32x4 acc[2][2]; acc[0][0] = acc[0][1] = acc[1][0] = acc[1][1] = z4;
        pass32p(As, lm, q, P, acc);        // acc[0]=z2, acc[1]=zg
#pragma unroll
        for (int rf = 0; rf < 2; ++rf)
#pragma unroll
          for (int r = 0; r < 4; ++r) {
            const int row = mb + rf * 16 + q * 4 + r;
            const int col = colw + lm;
            const size_t idx = (size_t)row * Hh + col;
            const float u = (s == 0) ? 1.f
                : 1.f / (1.f + expf(-(acc[1][rf][r] + pg1v[rf][r])));
            const float hn = tanhf(acc[0][rf][r] + p2v[rf][r]);
            const float nv = fmaf(u, hn - hpv[rf][r], hpv[rf][r]);
            p.h2f[idx] = nv;
            const short hv = f2bf(nv);
            ST_BF16_PAIR(h2out, row, col, hv);
          }
      }
    } else {                               // ---- out(s-1) ----
      if (ph >= 3) {
        const int to = ph - 3;
        BPre P;
        if (wv < 2) prefillB(P, B0, st0, B1, st1, lm, q);
        const float* po1s = p.po1f + (size_t)(to % 3) * (Bb * Oo);
        float pv[2][2][4];
        if (wv < 2) {
#pragma unroll
          for (int n = 0; n < 2; ++n)
#pragma unroll
            for (int rf = 0; rf < 2; ++rf)
#pragma unroll
              for (int r = 0; r < 4; ++r)
                pv[n][rf][r] = ldf(po1s + (size_t)(mb + rf * 16 + q * 4 + r) * Oo
                                   + colw + n * 16 + lm);
        }
        stage32(As, h2prev + (size_t)mb * Hh, tid);
        __syncthreads();
        if (wv < 2) {
          f32x4 acc[2][2]; acc[0][0] = acc[0][1] = acc[1][0] = acc[1][1] = z4;
          pass32p(As, lm, q, P, acc);
#pragma unroll
          for (int n = 0; n < 2; ++n)
#pragma unroll
            for (int rf = 0; rf < 2; ++rf)
#pragma unroll
              for (int r = 0; r < 4; ++r) {
                const int row = mb + rf * 16 + q * 4 + r;
                const int col = colw + n * 16 + lm;
                p.out[(size_t)row * (Tt * Oo) + (size_t)to * Oo + col] =
                    pv[n][rf][r] + tanhf(acc[n][rf][r] + (n ? bias1 : bias0));
              }
        }
      }
    }
    ++gen;
    grid_barrier(p.flags, gen, bid, tid);
  }
}

// pre_x[t][b][j] = x[b,t,:] @ W_ih1[j,:] + b_ih1[j] + b_hh1[j]  (stored bf16)
__global__ void __launch_bounds__(256) prex_kernel(
    const float* __restrict__ x, const float* __restrict__ wih1,
    const float* __restrict__ b_ih1, const float* __restrict__ b_hh1,
    short* __restrict__ prex) {
  const int tid = threadIdx.x;
  const int lane = tid & 63;
  const int wv = tid >> 6;
  const int lm = lane & 15;
  const int q = lane >> 4;
  const int bm = blockIdx.x >> 4;
  const int bn = blockIdx.x & 15;
  const int rowbase = bm * 64;
  const int col = bn * 64 + wv * 16 + lm;

  const f32x4 z4 = {0.f, 0.f, 0.f, 0.f};
  f32x4 acc[4];
#pragma unroll
  for (int mt = 0; mt < 4; ++mt) acc[mt] = z4;

#pragma unroll
  for (int kc = 0; kc < 2; ++kc) {
    const float* bp = wih1 + col * 64 + kc * 32 + q * 8;
    bf16x8 bf;
#pragma unroll
    for (int j = 0; j < 8; ++j) bf[j] = f2bf(bp[j]);
#pragma unroll
    for (int mt = 0; mt < 4; ++mt) {
      const float* ap = x + (size_t)(rowbase + mt * 16 + lm) * 64 + kc * 32 + q * 8;
      bf16x8 af;
#pragma unroll
      for (int j = 0; j < 8; ++j) af[j] = f2bf(ap[j]);
      acc[mt] = __builtin_amdgcn_mfma_f32_16x16x32_bf16(af, bf, acc[mt], 0, 0, 0);
    }
  }
  const float bia = b_ih1[col] + b_hh1[col];
#pragma unroll
  for (int mt = 0; mt < 4; ++mt) {
#pragma unroll
    for (int r = 0; r < 4; ++r) {
      const int row = rowbase + mt * 16 + q * 4 + r;  // row = b*256 + t
      const int b  = row >> 8;
      const int tt = row & 255;
      prex[((size_t)tt * Bb + b) * Hh + col] = f2bf(acc[mt][r] + bia);
    }
  }
}

__global__ void conv_kernel(const float* __restrict__ s, short* __restrict__ d, int n) {
  int i = blockIdx.x * blockDim.x + threadIdx.x;
  const int stride = gridDim.x * blockDim.x;
  for (; i < n; i += stride) d[i] = f2bf(s[i]);
}

__global__ void init_kernel(short* h1a, short* h1b, short* h2a, short* h2b,
                            float* h2f, unsigned* flags) {
  const int i = blockIdx.x * blockDim.x + threadIdx.x;  // exactly 128*1024
  h1a[i] = 0; h1b[i] = 0; h2a[i] = 0; h2b[i] = 0; h2f[i] = 0.f;
  if (i < 256) flags[i * FLAG_STRIDE] = (i < NBLK) ? 0u : 0xFFFFFFFFu;
}

extern "C" void kernel_launch(void* const* d_in, const int* in_sizes, int n_in,
                              void* d_out, int out_size, void* d_ws, size_t ws_size,
                              hipStream_t stream) {
  (void)in_sizes; (void)n_in; (void)out_size; (void)ws_size;
  const float* x      = (const float*)d_in[0];
  const float* W_ih1  = (const float*)d_in[1];
  const float* b_ih1  = (const float*)d_in[2];
  const float* W_hh1  = (const float*)d_in[3];
  const float* b_hh1  = (const float*)d_in[4];
  const float* W_ih2  = (const float*)d_in[5];
  const float* b_ih2  = (const float*)d_in[6];
  const float* W_hh2  = (const float*)d_in[7];
  const float* b_hh2  = (const float*)d_in[8];
  const float* Wg     = (const float*)d_in[9];
  const float* bg     = (const float*)d_in[10];
  const float* Wo1    = (const float*)d_in[11];
  const float* bo1    = (const float*)d_in[12];
  const float* Wo2    = (const float*)d_in[13];
  const float* bo2    = (const float*)d_in[14];

  char* ws = (char*)d_ws;
  size_t off = 0;
  auto alloc = [&](size_t bytes) -> void* {
    void* ptr = ws + off;
    off += (bytes + 255) & ~(size_t)255;
    return ptr;
  };
  short* whh1 = (short*)alloc((size_t)Hh * Hh * 2);
  short* wih2 = (short*)alloc((size_t)Hh * Hh * 2);
  short* whh2 = (short*)alloc((size_t)Hh * Hh * 2);
  short* wg   = (short*)alloc((size_t)Hh * 2 * Hh * 2);
  short* wo1  = (short*)alloc((size_t)Oo * Hh * 2);
  short* wo2  = (short*)alloc((size_t)Oo * Hh * 2);
  short* prex = (short*)alloc((size_t)Bb * Tt * Hh * 2);
  short* h1a  = (short*)alloc((size_t)Bb * Hh * 2);
  short* h1b  = (short*)alloc((size_t)Bb * Hh * 2);
  short* h2a  = (short*)alloc((size_t)Bb * Hh * 2);
  short* h2b  = (short*)alloc((size_t)Bb * Hh * 2);
  float* h2f  = (float*)alloc((size_t)Bb * Hh * 4);
  float* pre2f= (float*)alloc((size_t)2 * Bb * Hh * 4);
  float* pg1f = (float*)alloc((size_t)3 * Bb * Hh * 4);
  float* po1f = (float*)alloc((size_t)3 * Bb * Oo * 4);
  unsigned* flags = (unsigned*)alloc(256 * FLAG_STRIDE * 4);   // 32 KB

  conv_kernel<<<1024, 256, 0, stream>>>(W_hh1, whh1, Hh * Hh);
  conv_kernel<<<1024, 256, 0, stream>>>(W_ih2, wih2, Hh * Hh);
  conv_kernel<<<1024, 256, 0, stream>>>(W_hh2, whh2, Hh * Hh);
  conv_kernel<<<2048, 256, 0, stream>>>(Wg,    wg,   Hh * 2 * Hh);
  conv_kernel<<<256,  256, 0, stream>>>(Wo1,   wo1,  Oo * Hh);
  conv_kernel<<<256,  256, 0, stream>>>(Wo2,   wo2,  Oo * Hh);
  init_kernel<<<512, 256, 0, stream>>>(h1a, h1b, h2a, h2b, h2f, flags);
  prex_kernel<<<8192, 256, 0, stream>>>(x, W_ih1, b_ih1, b_hh1, prex);

  RP p;
  p.h1a = h1a; p.h1b = h1b; p.h2a = h2a; p.h2b = h2b;
  p.h2f = h2f; p.pre2f = pre2f; p.pg1f = pg1f; p.po1f = po1f;
  p.prex = prex;
  p.whh1 = whh1; p.wih2 = wih2; p.whh2 = whh2;
  p.wg = wg; p.wo1 = wo1; p.wo2 = wo2;
  p.b_ih2 = b_ih2; p.b_hh2 = b_hh2;
  p.bg = bg; p.bo1 = bo1; p.bo2 = bo2;
  p.out = (float*)d_out;
  p.flags = flags;

  rnn_kernel<<<NBLK, 256, 0, stream>>>(p);
}

// Round 5
// 3127.095 us; speedup vs baseline: 4.2540x; 1.0343x over previous
//
#include <hip/hip_runtime.h>
#include <cstddef>

using bf16x8 = __attribute__((ext_vector_type(8))) short;
using f32x4  = __attribute__((ext_vector_type(4))) float;

constexpr int Bb = 128;
constexpr int Tt = 256;
constexpr int Hh = 1024;
constexpr int Oo = 64;
constexpr int NBLK = 168;         // 32 H1 + 32 P2 + 32 PG + 4 PO + 64 H2U + 4 ZO
constexpr int FLAG_STRIDE = 32;   // dwords -> 128B between flags
constexpr int RS = 1048;          // LDS row stride in shorts (bank-spread, proven r0)

// flag group bases (slot == bid for posting)
constexpr int FH1 = 0;    // 32 blocks, posts t+1 after h1(t)
constexpr int FP2 = 32;   // 32 blocks, posts t+1 after pre2(t)
constexpr int FPG = 64;   // 32 blocks, posts t+1 after pg1(t)
constexpr int FPO = 96;   // 4 blocks,  posts t+1 after po1(t)
constexpr int FH2 = 100;  // 64 blocks, posts s+1 after h2(s)
constexpr int FZO = 164;  // 4 blocks,  posts ot+1 after out(ot)

__device__ __forceinline__ float bf2f(short s) {
  unsigned int u = ((unsigned int)(unsigned short)s) << 16;
  float f;
  __builtin_memcpy(&f, &u, 4);
  return f;
}
__device__ __forceinline__ short f2bf(float f) {
  unsigned int u;
  __builtin_memcpy(&u, &f, 4);
  u += 0x7fffu + ((u >> 16) & 1u);  // round-to-nearest-even
  return (short)(u >> 16);
}
__device__ __forceinline__ bf16x8 as_bf(int4 v) {
  union { int4 i; bf16x8 b; } u; u.i = v; return u.b;
}
__device__ __forceinline__ float ldf(const float* p) {
  return __hip_atomic_load((float*)p, __ATOMIC_RELAXED, __HIP_MEMORY_SCOPE_AGENT);
}
__device__ __forceinline__ void stf(float* p, float v) {
  __hip_atomic_store(p, v, __ATOMIC_RELAXED, __HIP_MEMORY_SCOPE_AGENT);
}
__device__ __forceinline__ unsigned ldu(const unsigned* p) {
  return __hip_atomic_load((unsigned*)p, __ATOMIC_RELAXED, __HIP_MEMORY_SCOPE_AGENT);
}
__device__ __forceinline__ short* sel3(short* a, short* b, short* c, int i) {
  return i == 0 ? a : (i == 1 ? b : c);
}
__device__ __forceinline__ const short* sel3c(const short* a, const short* b,
                                              const short* c, int i) {
  return i == 0 ? a : (i == 1 ? b : c);
}

// Agent-scope (sc1) coherent 16B load — LLC-coherent (cross-XCD state reads).
#define LD16A(d, p) asm volatile("global_load_dwordx4 %0, %1, off sc1" \
                                 : "=v"(d) : "v"((const void*)(p)))

// Stage one 32-row x 1024-col bf16 state slab into LDS.
// Counted waits are conservative-valid with earlier loads outstanding:
// vmcnt(N) waits all-but-N oldest, which always covers what each write needs.
__device__ __forceinline__ void stage32(short* As, const short* src, int tid) {
  const int row = tid >> 3;          // 0..31
  const int c0  = (tid & 7) * 8;     // shorts
  const short* gp = src + (size_t)row * Hh + c0;
  short* lp = As + row * RS + c0;
  int4 r0[8], r1[8];
#pragma unroll
  for (int j = 0; j < 8; ++j) LD16A(r0[j], gp + j * 64);
#pragma unroll
  for (int j = 0; j < 8; ++j) LD16A(r1[j], gp + 512 + j * 64);
  asm volatile("s_waitcnt vmcnt(8)" ::: "memory");
#pragma unroll
  for (int j = 0; j < 8; ++j) *(int4*)(lp + j * 64) = r0[j];
  asm volatile("s_waitcnt vmcnt(0)" ::: "memory");
#pragma unroll
  for (int j = 0; j < 8; ++j) *(int4*)(lp + 512 + j * 64) = r1[j];
}

// 6-deep B-ring (r3 structure, proven neutral-or-better).
struct BPre {
  const short *bp0, *bp1;
  int4 b0v[6], b1v[6];
};
__device__ __forceinline__ void prefillB(BPre& P,
    const short* __restrict__ B0, size_t st0,
    const short* __restrict__ B1, size_t st1, int lm, int q) {
  P.bp0 = B0 + (size_t)lm * st0 + q * 8;
  P.bp1 = B1 + (size_t)lm * st1 + q * 8;
#pragma unroll
  for (int c = 0; c < 5; ++c) {
    P.b0v[c] = *(const int4*)(P.bp0 + c * 32);
    P.b1v[c] = *(const int4*)(P.bp1 + c * 32);
  }
}
__device__ __forceinline__ void pass32p(const short* As, int lm, int q,
    BPre& P, f32x4 (&acc)[2][2]) {
  const short* ap0 = As + lm * RS + q * 8;
  const short* ap1 = ap0 + 16 * RS;
#pragma unroll
  for (int c = 0; c < 32; ++c) {
    if (c + 5 < 32) {
      P.b0v[(c + 5) % 6] = *(const int4*)(P.bp0 + (c + 5) * 32);
      P.b1v[(c + 5) % 6] = *(const int4*)(P.bp1 + (c + 5) * 32);
    }
    const bf16x8 a0 = as_bf(*(const int4*)(ap0 + c * 32));
    const bf16x8 a1 = as_bf(*(const int4*)(ap1 + c * 32));
    const bf16x8 b0 = as_bf(P.b0v[c % 6]);
    const bf16x8 b1 = as_bf(P.b1v[c % 6]);
    acc[0][0] = __builtin_amdgcn_mfma_f32_16x16x32_bf16(a0, b0, acc[0][0], 0, 0, 0);
    acc[0][1] = __builtin_amdgcn_mfma_f32_16x16x32_bf16(a1, b0, acc[0][1], 0, 0, 0);
    acc[1][0] = __builtin_amdgcn_mfma_f32_16x16x32_bf16(a0, b1, acc[1][0], 0, 0, 0);
    acc[1][1] = __builtin_amdgcn_mfma_f32_16x16x32_bf16(a1, b1, acc[1][1], 0, 0, 0);
  }
}

// Dataflow sync: poll one producer group's flags until all >= gen.
// Called by wave 0 only (tid < 64); mask = group_size-1 (pow2 cover).
__device__ __forceinline__ void poll_ge(const unsigned* flags, int base,
                                        int mask, unsigned gen) {
  const unsigned* f = flags + (size_t)(base + (threadIdx.x & mask)) * FLAG_STRIDE;
  while (!__all(ldu(f) >= gen))
    __builtin_amdgcn_s_sleep(2);
}

// Release: drain this wave's stores, block-sync, then tid0 posts flag.
#define POST_FLAG(GEN) do {                                                \
    asm volatile("s_waitcnt vmcnt(0) lgkmcnt(0)" ::: "memory");            \
    __syncthreads();                                                       \
    if (tid == 0)                                                          \
      __hip_atomic_store(p.flags + (size_t)bid * FLAG_STRIDE, (unsigned)(GEN), \
                         __ATOMIC_RELAXED, __HIP_MEMORY_SCOPE_AGENT);      \
  } while (0)

#define ST_BF16_PAIR(BASE, ROW, COL, HV) do {                              \
    const int _ov = __shfl_xor((int)(unsigned short)(HV), 1, 64);          \
    if ((lm & 1) == 0) {                                                   \
      const unsigned _pk = (unsigned)(unsigned short)(HV) | ((unsigned)_ov << 16); \
      __hip_atomic_store((unsigned*)((BASE) + (size_t)(ROW) * Hh + (COL)), _pk, \
                         __ATOMIC_RELAXED, __HIP_MEMORY_SCOPE_AGENT);      \
    } } while (0)

struct RP {
  short *h1r0, *h1r1, *h1r2;        // h1 bf16 ring (3)
  short *h2r0, *h2r1, *h2r2;        // h2 bf16 ring (3)
  float *h2f;                       // h2 f32 master (block-local tiles)
  float *pre2f;                     // 3 slots: Wih2@h1(t)+b_ih2+b_hh2
  float *pg1f;                      // 4 slots: Wg1@h1(t)+bg
  float *po1f;                      // 4 slots: tanh(Wo1@h1(t)+bo1)
  const short* prex;
  const short *whh1, *wih2, *whh2, *wg, *wo1, *wo2;
  const float *b_ih2, *b_hh2, *bg, *bo1, *bo2;
  float* out;
  unsigned* flags;
};

// DATAFLOW edition: no grid barrier. Each role advances on producer flags;
// ring-depth gates bound run-ahead. Dependency graph (X(step) <- Y(step')):
//   H1(t)  <- fH1>=t, [t>=3] fP2,fPG>=t-2, fPO>=t-2        (h1 ring 3)
//   P2(t)  <- fH1>=t+1, [t>=3] fH2>=t-2                    (pre2 ring 3)
//   PG(t)  <- fH1>=t+1, [t>=4] fH2>=t-2                    (pg1 ring 4)
//   PO(t)  <- fH1>=t+1, [t>=4] fZO>=t-3                    (po1 ring 4)
//   H2U(s) <- fP2>=s+1, [s>=1] fPG>=s, fH2>=s, [s>=3] fZO>=s-2  (h2 ring 3)
//   ZO(ot) <- fH2>=ot+1, fPO>=ot+1
// All waits reference strictly earlier steps -> acyclic -> deadlock-free.
__global__ void __launch_bounds__(256, 1) rnn_kernel(RP p) {
  __shared__ short As[32 * RS];     // 67072 B
  const int tid = threadIdx.x;
  const int lane = tid & 63;
  const int wv = tid >> 6;
  const int lm = lane & 15;
  const int q = lane >> 4;
  const int bid = blockIdx.x;

  int role, mb, cb;
  if      (bid < 32)  { role = 0; mb = (bid >> 3) * 32;         cb = (bid & 7) * 128; }
  else if (bid < 64)  { role = 1; mb = ((bid - 32) >> 3) * 32;  cb = ((bid - 32) & 7) * 128; }
  else if (bid < 96)  { role = 2; mb = ((bid - 64) >> 3) * 32;  cb = ((bid - 64) & 7) * 128; }
  else if (bid < 100) { role = 3; mb = (bid - 96) * 32;         cb = 0; }
  else if (bid < 164) { role = 4; mb = ((bid - 100) >> 4) * 32; cb = ((bid - 100) & 15) * 64; }
  else                { role = 5; mb = (bid - 164) * 32;        cb = 0; }

  int colw;
  if (role == 4) colw = cb + wv * 16;                 // 16 cols/wave, 2 streams
  else if (role == 3 || role == 5) colw = (wv & 1) * 32;  // 64-col heads
  else colw = cb + wv * 32;

  float bias0 = 0.f, bias1 = 0.f;
  if (role == 1) {
    bias0 = p.b_ih2[colw + lm] + p.b_hh2[colw + lm];
    bias1 = p.b_ih2[colw + 16 + lm] + p.b_hh2[colw + 16 + lm];
  } else if (role == 2) {
    bias0 = p.bg[colw + lm]; bias1 = p.bg[colw + 16 + lm];
  } else if (role == 3) {
    bias0 = p.bo1[colw + lm]; bias1 = p.bo1[colw + 16 + lm];
  } else if (role == 5) {
    bias0 = p.bo2[colw + lm]; bias1 = p.bo2[colw + 16 + lm];
  }

  const short* B0; const short* B1;
  size_t st0 = Hh, st1 = Hh;
  if      (role == 0) { B0 = p.whh1 + (size_t)colw * Hh; B1 = p.whh1 + (size_t)(colw + 16) * Hh; }
  else if (role == 1) { B0 = p.wih2 + (size_t)colw * Hh; B1 = p.wih2 + (size_t)(colw + 16) * Hh; }
  else if (role == 2) { B0 = p.wg + (size_t)colw * (2 * Hh); B1 = p.wg + (size_t)(colw + 16) * (2 * Hh); st0 = st1 = 2 * Hh; }
  else if (role == 3) { B0 = p.wo1 + (size_t)colw * Hh; B1 = p.wo1 + (size_t)(colw + 16) * Hh; }
  else if (role == 4) { B0 = p.whh2 + (size_t)colw * Hh; B1 = p.wg + Hh + (size_t)colw * (2 * Hh); st1 = 2 * Hh; }
  else                { B0 = p.wo2 + (size_t)colw * Hh; B1 = p.wo2 + (size_t)(colw + 16) * Hh; }

  const size_t HS = (size_t)Bb * Hh;
  const f32x4 z4 = {0.f, 0.f, 0.f, 0.f};

  if (role == 0) {                       // ============ H1 chain ============
    for (int t = 0; t < Tt; ++t) {
      BPre P; prefillB(P, B0, st0, B1, st1, lm, q);
      short prs[2][2][4];
      const short* pr = p.prex + (size_t)t * HS;
#pragma unroll
      for (int n = 0; n < 2; ++n)
#pragma unroll
        for (int rf = 0; rf < 2; ++rf)
#pragma unroll
          for (int r = 0; r < 4; ++r)
            prs[n][rf][r] = pr[(size_t)(mb + rf * 16 + q * 4 + r) * Hh + colw + n * 16 + lm];
      if (tid < 64) {
        if (t >= 1) poll_ge(p.flags, FH1, 31, (unsigned)t);
        if (t >= 3) {
          poll_ge(p.flags, FP2, 31, (unsigned)(t - 2));
          poll_ge(p.flags, FPG, 31, (unsigned)(t - 2));
          poll_ge(p.flags, FPO, 3,  (unsigned)(t - 2));
        }
      }
      __syncthreads();
      const short* h1prev = sel3c(p.h1r0, p.h1r1, p.h1r2, (t + 2) % 3);
      stage32(As, h1prev + (size_t)mb * Hh, tid);
      __syncthreads();
      f32x4 acc[2][2]; acc[0][0] = acc[0][1] = acc[1][0] = acc[1][1] = z4;
      pass32p(As, lm, q, P, acc);
      short* h1out = sel3(p.h1r0, p.h1r1, p.h1r2, t % 3);
#pragma unroll
      for (int n = 0; n < 2; ++n)
#pragma unroll
        for (int rf = 0; rf < 2; ++rf)
#pragma unroll
          for (int r = 0; r < 4; ++r) {
            const int row = mb + rf * 16 + q * 4 + r;
            const int col = colw + n * 16 + lm;
            const short hv = f2bf(tanhf(acc[n][rf][r] + bf2f(prs[n][rf][r])));
            ST_BF16_PAIR(h1out, row, col, hv);
          }
      POST_FLAG(t + 1);
    }
  } else if (role == 1) {                // ============ pre2(t) ============
    for (int t = 0; t < Tt; ++t) {
      BPre P; prefillB(P, B0, st0, B1, st1, lm, q);
      if (tid < 64) {
        poll_ge(p.flags, FH1, 31, (unsigned)(t + 1));
        if (t >= 3) poll_ge(p.flags, FH2, 63, (unsigned)(t - 2));
      }
      __syncthreads();
      const short* h1cur = sel3c(p.h1r0, p.h1r1, p.h1r2, t % 3);
      stage32(As, h1cur + (size_t)mb * Hh, tid);
      __syncthreads();
      f32x4 acc[2][2]; acc[0][0] = acc[0][1] = acc[1][0] = acc[1][1] = z4;
      pass32p(As, lm, q, P, acc);
      float* dst = p.pre2f + (size_t)(t % 3) * HS;
#pragma unroll
      for (int n = 0; n < 2; ++n)
#pragma unroll
        for (int rf = 0; rf < 2; ++rf)
#pragma unroll
          for (int r = 0; r < 4; ++r) {
            const int row = mb + rf * 16 + q * 4 + r;
            const int col = colw + n * 16 + lm;
            stf(dst + (size_t)row * Hh + col, acc[n][rf][r] + (n ? bias1 : bias0));
          }
      POST_FLAG(t + 1);
    }
  } else if (role == 2) {                // ============ pg1(t) ============
    for (int t = 0; t < Tt; ++t) {
      BPre P; prefillB(P, B0, st0, B1, st1, lm, q);
      if (tid < 64) {
        poll_ge(p.flags, FH1, 31, (unsigned)(t + 1));
        if (t >= 4) poll_ge(p.flags, FH2, 63, (unsigned)(t - 2));
      }
      __syncthreads();
      const short* h1cur = sel3c(p.h1r0, p.h1r1, p.h1r2, t % 3);
      stage32(As, h1cur + (size_t)mb * Hh, tid);
      __syncthreads();
      f32x4 acc[2][2]; acc[0][0] = acc[0][1] = acc[1][0] = acc[1][1] = z4;
      pass32p(As, lm, q, P, acc);
      float* dst = p.pg1f + (size_t)(t % 4) * HS;
#pragma unroll
      for (int n = 0; n < 2; ++n)
#pragma unroll
        for (int rf = 0; rf < 2; ++rf)
#pragma unroll
          for (int r = 0; r < 4; ++r) {
            const int row = mb + rf * 16 + q * 4 + r;
            const int col = colw + n * 16 + lm;
            stf(dst + (size_t)row * Hh + col, acc[n][rf][r] + (n ? bias1 : bias0));
          }
      POST_FLAG(t + 1);
    }
  } else if (role == 3) {                // ============ po1(t) ============
    for (int t = 0; t < Tt; ++t) {
      BPre P;
      if (wv < 2) prefillB(P, B0, st0, B1, st1, lm, q);
      if (tid < 64) {
        poll_ge(p.flags, FH1, 31, (unsigned)(t + 1));
        if (t >= 4) poll_ge(p.flags, FZO, 3, (unsigned)(t - 3));
      }
      __syncthreads();
      const short* h1cur = sel3c(p.h1r0, p.h1r1, p.h1r2, t % 3);
      stage32(As, h1cur + (size_t)mb * Hh, tid);
      __syncthreads();
      if (wv < 2) {
        f32x4 acc[2][2]; acc[0][0] = acc[0][1] = acc[1][0] = acc[1][1] = z4;
        pass32p(As, lm, q, P, acc);
        float* dst = p.po1f + (size_t)(t % 4) * (Bb * Oo);
#pragma unroll
        for (int n = 0; n < 2; ++n)
#pragma unroll
          for (int rf = 0; rf < 2; ++rf)
#pragma unroll
            for (int r = 0; r < 4; ++r) {
              const int row = mb + rf * 16 + q * 4 + r;
              const int col = colw + n * 16 + lm;
              stf(dst + (size_t)row * Oo + col,
                  tanhf(acc[n][rf][r] + (n ? bias1 : bias0)));
            }
      }
      POST_FLAG(t + 1);
    }
  } else if (role == 4) {                // ============ H2 step s ============
    for (int s = 0; s < Tt; ++s) {
      BPre P; prefillB(P, B0, st0, B1, st1, lm, q);
      if (tid < 64) {
        poll_ge(p.flags, FP2, 31, (unsigned)(s + 1));
        if (s >= 1) {
          poll_ge(p.flags, FPG, 31, (unsigned)s);
          poll_ge(p.flags, FH2, 63, (unsigned)s);
        }
        if (s >= 3) poll_ge(p.flags, FZO, 3, (unsigned)(s - 2));
      }
      __syncthreads();
      float p2v[2][4], pg1v[2][4], hpv[2][4];
      const float* pre2s = p.pre2f + (size_t)(s % 3) * HS;
      const float* pg1s  = p.pg1f + (size_t)((s + 3) % 4) * HS;
#pragma unroll
      for (int rf = 0; rf < 2; ++rf)
#pragma unroll
        for (int r = 0; r < 4; ++r) {
          const size_t idx = (size_t)(mb + rf * 16 + q * 4 + r) * Hh + colw + lm;
          p2v[rf][r] = ldf(pre2s + idx);
          pg1v[rf][r] = (s > 0) ? ldf(pg1s + idx) : 0.f;
          hpv[rf][r] = p.h2f[idx];       // block-local plain RW
        }
      const short* h2prev = sel3c(p.h2r0, p.h2r1, p.h2r2, (s + 2) % 3);
      stage32(As, h2prev + (size_t)mb * Hh, tid);
      __syncthreads();
      f32x4 acc[2][2]; acc[0][0] = acc[0][1] = acc[1][0] = acc[1][1] = z4;
      pass32p(As, lm, q, P, acc);        // acc[0]=z2, acc[1]=zg
      short* h2out = sel3(p.h2r0, p.h2r1, p.h2r2, s % 3);
#pragma unroll
      for (int rf = 0; rf < 2; ++rf)
#pragma unroll
        for (int r = 0; r < 4; ++r) {
          const int row = mb + rf * 16 + q * 4 + r;
          const int col = colw + lm;
          const size_t idx = (size_t)row * Hh + col;
          const float u = (s == 0) ? 1.f
              : 1.f / (1.f + expf(-(acc[1][rf][r] + pg1v[rf][r])));
          const float hn = tanhf(acc[0][rf][r] + p2v[rf][r]);
          const float nv = fmaf(u, hn - hpv[rf][r], hpv[rf][r]);
          p.h2f[idx] = nv;
          const short hv = f2bf(nv);
          ST_BF16_PAIR(h2out, row, col, hv);
        }
      POST_FLAG(s + 1);
    }
  } else {                               // ============ out(ot) ============
    for (int ot = 0; ot < Tt; ++ot) {
      BPre P;
      if (wv < 2) prefillB(P, B0, st0, B1, st1, lm, q);
      if (tid < 64) {
        poll_ge(p.flags, FH2, 63, (unsigned)(ot + 1));
        poll_ge(p.flags, FPO, 3,  (unsigned)(ot + 1));
      }
      __syncthreads();
      const float* po1s = p.po1f + (size_t)(ot % 4) * (Bb * Oo);
      float pv[2][2][4];
      if (wv < 2) {
#pragma unroll
        for (int n = 0; n < 2; ++n)
#pragma unroll
          for (int rf = 0; rf < 2; ++rf)
#pragma unroll
            for (int r = 0; r < 4; ++r)
              pv[n][rf][r] = ldf(po1s + (size_t)(mb + rf * 16 + q * 4 + r) * Oo
                                 + colw + n * 16 + lm);
      }
      const short* h2cur = sel3c(p.h2r0, p.h2r1, p.h2r2, ot % 3);
      stage32(As, h2cur + (size_t)mb * Hh, tid);
      __syncthreads();
      if (wv < 2) {
        f32x4 acc[2][2]; acc[0][0] = acc[0][1] = acc[1][0] = acc[1][1] = z4;
        pass32p(As, lm, q, P, acc);
#pragma unroll
        for (int n = 0; n < 2; ++n)
#pragma unroll
          for (int rf = 0; rf < 2; ++rf)
#pragma unroll
            for (int r = 0; r < 4; ++r) {
              const int row = mb + rf * 16 + q * 4 + r;
              const int col = colw + n * 16 + lm;
              p.out[(size_t)row * (Tt * Oo) + (size_t)ot * Oo + col] =
                  pv[n][rf][r] + tanhf(acc[n][rf][r] + (n ? bias1 : bias0));
            }
      }
      POST_FLAG(ot + 1);
    }
  }
}

// pre_x[t][b][j] = x[b,t,:] @ W_ih1[j,:] + b_ih1[j] + b_hh1[j]  (stored bf16)
__global__ void __launch_bounds__(256) prex_kernel(
    const float* __restrict__ x, const float* __restrict__ wih1,
    const float* __restrict__ b_ih1, const float* __restrict__ b_hh1,
    short* __restrict__ prex) {
  const int tid = threadIdx.x;
  const int lane = tid & 63;
  const int wv = tid >> 6;
  const int lm = lane & 15;
  const int q = lane >> 4;
  const int bm = blockIdx.x >> 4;
  const int bn = blockIdx.x & 15;
  const int rowbase = bm * 64;
  const int col = bn * 64 + wv * 16 + lm;

  const f32x4 z4 = {0.f, 0.f, 0.f, 0.f};
  f32x4 acc[4];
#pragma unroll
  for (int mt = 0; mt < 4; ++mt) acc[mt] = z4;

#pragma unroll
  for (int kc = 0; kc < 2; ++kc) {
    const float* bp = wih1 + col * 64 + kc * 32 + q * 8;
    bf16x8 bf;
#pragma unroll
    for (int j = 0; j < 8; ++j) bf[j] = f2bf(bp[j]);
#pragma unroll
    for (int mt = 0; mt < 4; ++mt) {
      const float* ap = x + (size_t)(rowbase + mt * 16 + lm) * 64 + kc * 32 + q * 8;
      bf16x8 af;
#pragma unroll
      for (int j = 0; j < 8; ++j) af[j] = f2bf(ap[j]);
      acc[mt] = __builtin_amdgcn_mfma_f32_16x16x32_bf16(af, bf, acc[mt], 0, 0, 0);
    }
  }
  const float bia = b_ih1[col] + b_hh1[col];
#pragma unroll
  for (int mt = 0; mt < 4; ++mt) {
#pragma unroll
    for (int r = 0; r < 4; ++r) {
      const int row = rowbase + mt * 16 + q * 4 + r;  // row = b*256 + t
      const int b  = row >> 8;
      const int tt = row & 255;
      prex[((size_t)tt * Bb + b) * Hh + col] = f2bf(acc[mt][r] + bia);
    }
  }
}

__global__ void conv_kernel(const float* __restrict__ s, short* __restrict__ d, int n) {
  int i = blockIdx.x * blockDim.x + threadIdx.x;
  const int stride = gridDim.x * blockDim.x;
  for (; i < n; i += stride) d[i] = f2bf(s[i]);
}

__global__ void init_kernel(short* h1r0, short* h1r1, short* h1r2,
                            short* h2r0, short* h2r1, short* h2r2,
                            float* h2f, unsigned* flags) {
  const int i = blockIdx.x * blockDim.x + threadIdx.x;  // exactly 128*1024
  h1r0[i] = 0; h1r1[i] = 0; h1r2[i] = 0;
  h2r0[i] = 0; h2r1[i] = 0; h2r2[i] = 0;
  h2f[i] = 0.f;
  if (i < 256) flags[i * FLAG_STRIDE] = 0u;
}

extern "C" void kernel_launch(void* const* d_in, const int* in_sizes, int n_in,
                              void* d_out, int out_size, void* d_ws, size_t ws_size,
                              hipStream_t stream) {
  (void)in_sizes; (void)n_in; (void)out_size; (void)ws_size;
  const float* x      = (const float*)d_in[0];
  const float* W_ih1  = (const float*)d_in[1];
  const float* b_ih1  = (const float*)d_in[2];
  const float* W_hh1  = (const float*)d_in[3];
  const float* b_hh1  = (const float*)d_in[4];
  const float* W_ih2  = (const float*)d_in[5];
  const float* b_ih2  = (const float*)d_in[6];
  const float* W_hh2  = (const float*)d_in[7];
  const float* b_hh2  = (const float*)d_in[8];
  const float* Wg     = (const float*)d_in[9];
  const float* bg     = (const float*)d_in[10];
  const float* Wo1    = (const float*)d_in[11];
  const float* bo1    = (const float*)d_in[12];
  const float* Wo2    = (const float*)d_in[13];
  const float* bo2    = (const float*)d_in[14];

  char* ws = (char*)d_ws;
  size_t off = 0;
  auto alloc = [&](size_t bytes) -> void* {
    void* ptr = ws + off;
    off += (bytes + 255) & ~(size_t)255;
    return ptr;
  };
  short* whh1 = (short*)alloc((size_t)Hh * Hh * 2);
  short* wih2 = (short*)alloc((size_t)Hh * Hh * 2);
  short* whh2 = (short*)alloc((size_t)Hh * Hh * 2);
  short* wg   = (short*)alloc((size_t)Hh * 2 * Hh * 2);
  short* wo1  = (short*)alloc((size_t)Oo * Hh * 2);
  short* wo2  = (short*)alloc((size_t)Oo * Hh * 2);
  short* prex = (short*)alloc((size_t)Bb * Tt * Hh * 2);
  short* h1r0 = (short*)alloc((size_t)Bb * Hh * 2);
  short* h1r1 = (short*)alloc((size_t)Bb * Hh * 2);
  short* h1r2 = (short*)alloc((size_t)Bb * Hh * 2);
  short* h2r0 = (short*)alloc((size_t)Bb * Hh * 2);
  short* h2r1 = (short*)alloc((size_t)Bb * Hh * 2);
  short* h2r2 = (short*)alloc((size_t)Bb * Hh * 2);
  float* h2f  = (float*)alloc((size_t)Bb * Hh * 4);
  float* pre2f= (float*)alloc((size_t)3 * Bb * Hh * 4);
  float* pg1f = (float*)alloc((size_t)4 * Bb * Hh * 4);
  float* po1f = (float*)alloc((size_t)4 * Bb * Oo * 4);
  unsigned* flags = (unsigned*)alloc(256 * FLAG_STRIDE * 4);   // 32 KB

  conv_kernel<<<1024, 256, 0, stream>>>(W_hh1, whh1, Hh * Hh);
  conv_kernel<<<1024, 256, 0, stream>>>(W_ih2, wih2, Hh * Hh);
  conv_kernel<<<1024, 256, 0, stream>>>(W_hh2, whh2, Hh * Hh);
  conv_kernel<<<2048, 256, 0, stream>>>(Wg,    wg,   Hh * 2 * Hh);
  conv_kernel<<<256,  256, 0, stream>>>(Wo1,   wo1,  Oo * Hh);
  conv_kernel<<<256,  256, 0, stream>>>(Wo2,   wo2,  Oo * Hh);
  init_kernel<<<512, 256, 0, stream>>>(h1r0, h1r1, h1r2, h2r0, h2r1, h2r2, h2f, flags);
  prex_kernel<<<8192, 256, 0, stream>>>(x, W_ih1, b_ih1, b_hh1, prex);

  RP p;
  p.h1r0 = h1r0; p.h1r1 = h1r1; p.h1r2 = h1r2;
  p.h2r0 = h2r0; p.h2r1 = h2r1; p.h2r2 = h2r2;
  p.h2f = h2f; p.pre2f = pre2f; p.pg1f = pg1f; p.po1f = po1f;
  p.prex = prex;
  p.whh1 = whh1; p.wih2 = wih2; p.whh2 = whh2;
  p.wg = wg; p.wo1 = wo1; p.wo2 = wo2;
  p.b_ih2 = b_ih2; p.b_hh2 = b_hh2;
  p.bg = bg; p.bo1 = bo1; p.bo2 = bo2;
  p.out = (float*)d_out;
  p.flags = flags;

  rnn_kernel<<<NBLK, 256, 0, stream>>>(p);
}

// Round 6
// 3117.359 us; speedup vs baseline: 4.2673x; 1.0031x over previous
//
#include <hip/hip_runtime.h>
#include <cstddef>

using bf16x8 = __attribute__((ext_vector_type(8))) short;
using f32x4  = __attribute__((ext_vector_type(4))) float;

constexpr int Bb = 128;
constexpr int Tt = 256;
constexpr int Hh = 1024;
constexpr int Oo = 64;
constexpr int NBLK = 168;         // 32 H1 + 32 P2 + 32 PG + 4 PO + 64 H2U + 4 ZO
constexpr int FLAG_STRIDE = 32;   // dwords -> 128B between flags
constexpr int RS = 1048;          // LDS row stride in shorts (bank-spread, proven r0)

// ring depths (deep: decouple backward overwrite gates from the chains)
constexpr int R_H1 = 8;
constexpr int R_H2 = 16;
constexpr int R_P2 = 6;
constexpr int R_PG = 6;
constexpr int R_PO = 16;

// flag group bases (slot == bid for posting)
constexpr int FH1 = 0;    // 32 blocks, posts t+1 after h1(t)
constexpr int FP2 = 32;   // 32 blocks, posts t+1 after pre2(t)
constexpr int FPG = 64;   // 32 blocks, posts t+1 after pg1(t)
constexpr int FPO = 96;   // 4 blocks,  posts t+1 after po1(t)
constexpr int FH2 = 100;  // 64 blocks, posts s+1 after h2(s)
constexpr int FZO = 164;  // 4 blocks,  posts ot+1 after out(ot)

__device__ __forceinline__ float bf2f(short s) {
  unsigned int u = ((unsigned int)(unsigned short)s) << 16;
  float f;
  __builtin_memcpy(&f, &u, 4);
  return f;
}
__device__ __forceinline__ short f2bf(float f) {
  unsigned int u;
  __builtin_memcpy(&u, &f, 4);
  u += 0x7fffu + ((u >> 16) & 1u);  // round-to-nearest-even
  return (short)(u >> 16);
}
__device__ __forceinline__ bf16x8 as_bf(int4 v) {
  union { int4 i; bf16x8 b; } u; u.i = v; return u.b;
}
__device__ __forceinline__ float ldf(const float* p) {
  return __hip_atomic_load((float*)p, __ATOMIC_RELAXED, __HIP_MEMORY_SCOPE_AGENT);
}
__device__ __forceinline__ void stf(float* p, float v) {
  __hip_atomic_store(p, v, __ATOMIC_RELAXED, __HIP_MEMORY_SCOPE_AGENT);
}
__device__ __forceinline__ unsigned ldu(const unsigned* p) {
  return __hip_atomic_load((unsigned*)p, __ATOMIC_RELAXED, __HIP_MEMORY_SCOPE_AGENT);
}

// Agent-scope (sc1) coherent 16B load — LLC-coherent (cross-XCD state reads).
#define LD16A(d, p) asm volatile("global_load_dwordx4 %0, %1, off sc1" \
                                 : "=v"(d) : "v"((const void*)(p)))

// Stage one 32-row x 1024-col bf16 state slab into LDS.
__device__ __forceinline__ void stage32(short* As, const short* src, int tid) {
  const int row = tid >> 3;          // 0..31
  const int c0  = (tid & 7) * 8;     // shorts
  const short* gp = src + (size_t)row * Hh + c0;
  short* lp = As + row * RS + c0;
  int4 r0[8], r1[8];
#pragma unroll
  for (int j = 0; j < 8; ++j) LD16A(r0[j], gp + j * 64);
#pragma unroll
  for (int j = 0; j < 8; ++j) LD16A(r1[j], gp + 512 + j * 64);
  asm volatile("s_waitcnt vmcnt(8)" ::: "memory");
#pragma unroll
  for (int j = 0; j < 8; ++j) *(int4*)(lp + j * 64) = r0[j];
  asm volatile("s_waitcnt vmcnt(0)" ::: "memory");
#pragma unroll
  for (int j = 0; j < 8; ++j) *(int4*)(lp + 512 + j * 64) = r1[j];
}

// 6-deep B-ring (proven structure).
struct BPre {
  const short *bp0, *bp1;
  int4 b0v[6], b1v[6];
};
__device__ __forceinline__ void prefillB(BPre& P,
    const short* __restrict__ B0, size_t st0,
    const short* __restrict__ B1, size_t st1, int lm, int q) {
  P.bp0 = B0 + (size_t)lm * st0 + q * 8;
  P.bp1 = B1 + (size_t)lm * st1 + q * 8;
#pragma unroll
  for (int c = 0; c < 5; ++c) {
    P.b0v[c] = *(const int4*)(P.bp0 + c * 32);
    P.b1v[c] = *(const int4*)(P.bp1 + c * 32);
  }
}
__device__ __forceinline__ void pass32p(const short* As, int lm, int q,
    BPre& P, f32x4 (&acc)[2][2]) {
  const short* ap0 = As + lm * RS + q * 8;
  const short* ap1 = ap0 + 16 * RS;
#pragma unroll
  for (int c = 0; c < 32; ++c) {
    if (c + 5 < 32) {
      P.b0v[(c + 5) % 6] = *(const int4*)(P.bp0 + (c + 5) * 32);
      P.b1v[(c + 5) % 6] = *(const int4*)(P.bp1 + (c + 5) * 32);
    }
    const bf16x8 a0 = as_bf(*(const int4*)(ap0 + c * 32));
    const bf16x8 a1 = as_bf(*(const int4*)(ap1 + c * 32));
    const bf16x8 b0 = as_bf(P.b0v[c % 6]);
    const bf16x8 b1 = as_bf(P.b1v[c % 6]);
    acc[0][0] = __builtin_amdgcn_mfma_f32_16x16x32_bf16(a0, b0, acc[0][0], 0, 0, 0);
    acc[0][1] = __builtin_amdgcn_mfma_f32_16x16x32_bf16(a1, b0, acc[0][1], 0, 0, 0);
    acc[1][0] = __builtin_amdgcn_mfma_f32_16x16x32_bf16(a0, b1, acc[1][0], 0, 0, 0);
    acc[1][1] = __builtin_amdgcn_mfma_f32_16x16x32_bf16(a1, b1, acc[1][1], 0, 0, 0);
  }
}

// Dataflow sync: poll one producer group's flags until all >= gen.
// Called by wave 0 only (tid < 64); mask = group_size-1 (pow2 cover).
__device__ __forceinline__ void poll_ge(const unsigned* flags, int base,
                                        int mask, unsigned gen) {
  const unsigned* f = flags + (size_t)(base + (threadIdx.x & mask)) * FLAG_STRIDE;
  while (!__all(ldu(f) >= gen))
    __builtin_amdgcn_s_sleep(2);
}

// Release: drain this wave's stores, block-sync, then tid0 posts flag.
#define POST_FLAG(GEN) do {                                                \
    asm volatile("s_waitcnt vmcnt(0) lgkmcnt(0)" ::: "memory");            \
    __syncthreads();                                                       \
    if (tid == 0)                                                          \
      __hip_atomic_store(p.flags + (size_t)bid * FLAG_STRIDE, (unsigned)(GEN), \
                         __ATOMIC_RELAXED, __HIP_MEMORY_SCOPE_AGENT);      \
  } while (0)

#define ST_BF16_PAIR(BASE, ROW, COL, HV) do {                              \
    const int _ov = __shfl_xor((int)(unsigned short)(HV), 1, 64);          \
    if ((lm & 1) == 0) {                                                   \
      const unsigned _pk = (unsigned)(unsigned short)(HV) | ((unsigned)_ov << 16); \
      __hip_atomic_store((unsigned*)((BASE) + (size_t)(ROW) * Hh + (COL)), _pk, \
                         __ATOMIC_RELAXED, __HIP_MEMORY_SCOPE_AGENT);      \
    } } while (0)

struct RP {
  short *h1ring;                    // 8  slots of [Bb x Hh] bf16
  short *h2ring;                    // 16 slots of [Bb x Hh] bf16
  float *h2f;                       // h2 f32 master (block-local tiles)
  float *pre2f;                     // 6 slots
  float *pg1f;                      // 6 slots
  float *po1f;                      // 16 slots of [Bb x Oo]
  const short* prex;
  const short *whh1, *wih2, *whh2, *wg, *wo1, *wo2;
  const float *b_ih2, *b_hh2, *bg, *bo1, *bo2;
  float* out;
  unsigned* flags;
};

// DEEP-RING dataflow. Near-critical edges: H1 chain (FH1>=t), P2<-H1 (lag1),
// H2U<-P2 (lag1), H2U chain. All overwrite gates have slack >= 4:
//   H1(t)  <- FH1>=t; [t>=8]  FP2,FPG,FPO >= t-7        (h1 ring 8)
//   P2(t)  <- FH1>=t+1; [t>=6] FH2 >= t-5               (pre2 ring 6)
//   PG(t)  <- FH1>=t+1; [t>=6] FH2 >= t-4               (pg1 ring 6)
//   PO(t)  <- FH1>=t+1; [t>=16] FZO >= t-15             (po1 ring 16)
//   H2U(s) <- FP2>=s+1; [s>=1] FPG>=s, FH2>=s; [s>=16] FZO >= s-15  (h2 ring 16)
//   ZO(ot) <- FH2>=ot+1, FPO>=ot+1
__global__ void __launch_bounds__(256, 1) rnn_kernel(RP p) {
  __shared__ short As[32 * RS];     // 67072 B
  const int tid = threadIdx.x;
  const int lane = tid & 63;
  const int wv = tid >> 6;
  const int lm = lane & 15;
  const int q = lane >> 4;
  const int bid = blockIdx.x;

  int role, mb, cb;
  if      (bid < 32)  { role = 0; mb = (bid >> 3) * 32;         cb = (bid & 7) * 128; }
  else if (bid < 64)  { role = 1; mb = ((bid - 32) >> 3) * 32;  cb = ((bid - 32) & 7) * 128; }
  else if (bid < 96)  { role = 2; mb = ((bid - 64) >> 3) * 32;  cb = ((bid - 64) & 7) * 128; }
  else if (bid < 100) { role = 3; mb = (bid - 96) * 32;         cb = 0; }
  else if (bid < 164) { role = 4; mb = ((bid - 100) >> 4) * 32; cb = ((bid - 100) & 15) * 64; }
  else                { role = 5; mb = (bid - 164) * 32;        cb = 0; }

  int colw;
  if (role == 4) colw = cb + wv * 16;                 // 16 cols/wave, 2 streams
  else if (role == 3 || role == 5) colw = (wv & 1) * 32;  // 64-col heads
  else colw = cb + wv * 32;

  float bias0 = 0.f, bias1 = 0.f;
  if (role == 1) {
    bias0 = p.b_ih2[colw + lm] + p.b_hh2[colw + lm];
    bias1 = p.b_ih2[colw + 16 + lm] + p.b_hh2[colw + 16 + lm];
  } else if (role == 2) {
    bias0 = p.bg[colw + lm]; bias1 = p.bg[colw + 16 + lm];
  } else if (role == 3) {
    bias0 = p.bo1[colw + lm]; bias1 = p.bo1[colw + 16 + lm];
  } else if (role == 5) {
    bias0 = p.bo2[colw + lm]; bias1 = p.bo2[colw + 16 + lm];
  }

  const short* B0; const short* B1;
  size_t st0 = Hh, st1 = Hh;
  if      (role == 0) { B0 = p.whh1 + (size_t)colw * Hh; B1 = p.whh1 + (size_t)(colw + 16) * Hh; }
  else if (role == 1) { B0 = p.wih2 + (size_t)colw * Hh; B1 = p.wih2 + (size_t)(colw + 16) * Hh; }
  else if (role == 2) { B0 = p.wg + (size_t)colw * (2 * Hh); B1 = p.wg + (size_t)(colw + 16) * (2 * Hh); st0 = st1 = 2 * Hh; }
  else if (role == 3) { B0 = p.wo1 + (size_t)colw * Hh; B1 = p.wo1 + (size_t)(colw + 16) * Hh; }
  else if (role == 4) { B0 = p.whh2 + (size_t)colw * Hh; B1 = p.wg + Hh + (size_t)colw * (2 * Hh); st1 = 2 * Hh; }
  else                { B0 = p.wo2 + (size_t)colw * Hh; B1 = p.wo2 + (size_t)(colw + 16) * Hh; }

  const size_t HS = (size_t)Bb * Hh;
  const f32x4 z4 = {0.f, 0.f, 0.f, 0.f};

  if (role == 0) {                       // ============ H1 chain ============
    for (int t = 0; t < Tt; ++t) {
      BPre P; prefillB(P, B0, st0, B1, st1, lm, q);
      short prs[2][2][4];
      const short* pr = p.prex + (size_t)t * HS;
#pragma unroll
      for (int n = 0; n < 2; ++n)
#pragma unroll
        for (int rf = 0; rf < 2; ++rf)
#pragma unroll
          for (int r = 0; r < 4; ++r)
            prs[n][rf][r] = pr[(size_t)(mb + rf * 16 + q * 4 + r) * Hh + colw + n * 16 + lm];
      if (tid < 64) {
        if (t >= 1) poll_ge(p.flags, FH1, 31, (unsigned)t);
        if (t >= 8) {
          poll_ge(p.flags, FP2, 31, (unsigned)(t - 7));
          poll_ge(p.flags, FPG, 31, (unsigned)(t - 7));
          poll_ge(p.flags, FPO, 3,  (unsigned)(t - 7));
        }
      }
      __syncthreads();
      const short* h1prev = p.h1ring + (size_t)((t + R_H1 - 1) % R_H1) * HS;
      stage32(As, h1prev + (size_t)mb * Hh, tid);
      __syncthreads();
      f32x4 acc[2][2]; acc[0][0] = acc[0][1] = acc[1][0] = acc[1][1] = z4;
      pass32p(As, lm, q, P, acc);
      short* h1out = p.h1ring + (size_t)(t % R_H1) * HS;
#pragma unroll
      for (int n = 0; n < 2; ++n)
#pragma unroll
        for (int rf = 0; rf < 2; ++rf)
#pragma unroll
          for (int r = 0; r < 4; ++r) {
            const int row = mb + rf * 16 + q * 4 + r;
            const int col = colw + n * 16 + lm;
            const short hv = f2bf(tanhf(acc[n][rf][r] + bf2f(prs[n][rf][r])));
            ST_BF16_PAIR(h1out, row, col, hv);
          }
      POST_FLAG(t + 1);
    }
  } else if (role == 1) {                // ============ pre2(t) ============
    for (int t = 0; t < Tt; ++t) {
      BPre P; prefillB(P, B0, st0, B1, st1, lm, q);
      if (tid < 64) {
        poll_ge(p.flags, FH1, 31, (unsigned)(t + 1));
        if (t >= R_P2) poll_ge(p.flags, FH2, 63, (unsigned)(t - 5));
      }
      __syncthreads();
      const short* h1cur = p.h1ring + (size_t)(t % R_H1) * HS;
      stage32(As, h1cur + (size_t)mb * Hh, tid);
      __syncthreads();
      f32x4 acc[2][2]; acc[0][0] = acc[0][1] = acc[1][0] = acc[1][1] = z4;
      pass32p(As, lm, q, P, acc);
      float* dst = p.pre2f + (size_t)(t % R_P2) * HS;
#pragma unroll
      for (int n = 0; n < 2; ++n)
#pragma unroll
        for (int rf = 0; rf < 2; ++rf)
#pragma unroll
          for (int r = 0; r < 4; ++r) {
            const int row = mb + rf * 16 + q * 4 + r;
            const int col = colw + n * 16 + lm;
            stf(dst + (size_t)row * Hh + col, acc[n][rf][r] + (n ? bias1 : bias0));
          }
      POST_FLAG(t + 1);
    }
  } else if (role == 2) {                // ============ pg1(t) ============
    for (int t = 0; t < Tt; ++t) {
      BPre P; prefillB(P, B0, st0, B1, st1, lm, q);
      if (tid < 64) {
        poll_ge(p.flags, FH1, 31, (unsigned)(t + 1));
        if (t >= R_PG) poll_ge(p.flags, FH2, 63, (unsigned)(t - 4));
      }
      __syncthreads();
      const short* h1cur = p.h1ring + (size_t)(t % R_H1) * HS;
      stage32(As, h1cur + (size_t)mb * Hh, tid);
      __syncthreads();
      f32x4 acc[2][2]; acc[0][0] = acc[0][1] = acc[1][0] = acc[1][1] = z4;
      pass32p(As, lm, q, P, acc);
      float* dst = p.pg1f + (size_t)(t % R_PG) * HS;
#pragma unroll
      for (int n = 0; n < 2; ++n)
#pragma unroll
        for (int rf = 0; rf < 2; ++rf)
#pragma unroll
          for (int r = 0; r < 4; ++r) {
            const int row = mb + rf * 16 + q * 4 + r;
            const int col = colw + n * 16 + lm;
            stf(dst + (size_t)row * Hh + col, acc[n][rf][r] + (n ? bias1 : bias0));
          }
      POST_FLAG(t + 1);
    }
  } else if (role == 3) {                // ============ po1(t) ============
    for (int t = 0; t < Tt; ++t) {
      BPre P;
      if (wv < 2) prefillB(P, B0, st0, B1, st1, lm, q);
      if (tid < 64) {
        poll_ge(p.flags, FH1, 31, (unsigned)(t + 1));
        if (t >= R_PO) poll_ge(p.flags, FZO, 3, (unsigned)(t - 15));
      }
      __syncthreads();
      const short* h1cur = p.h1ring + (size_t)(t % R_H1) * HS;
      stage32(As, h1cur + (size_t)mb * Hh, tid);
      __syncthreads();
      if (wv < 2) {
        f32x4 acc[2][2]; acc[0][0] = acc[0][1] = acc[1][0] = acc[1][1] = z4;
        pass32p(As, lm, q, P, acc);
        float* dst = p.po1f + (size_t)(t % R_PO) * (Bb * Oo);
#pragma unroll
        for (int n = 0; n < 2; ++n)
#pragma unroll
          for (int rf = 0; rf < 2; ++rf)
#pragma unroll
            for (int r = 0; r < 4; ++r) {
              const int row = mb + rf * 16 + q * 4 + r;
              const int col = colw + n * 16 + lm;
              stf(dst + (size_t)row * Oo + col,
                  tanhf(acc[n][rf][r] + (n ? bias1 : bias0)));
            }
      }
      POST_FLAG(t + 1);
    }
  } else if (role == 4) {                // ============ H2 step s ============
    for (int s = 0; s < Tt; ++s) {
      BPre P; prefillB(P, B0, st0, B1, st1, lm, q);
      if (tid < 64) {
        poll_ge(p.flags, FP2, 31, (unsigned)(s + 1));
        if (s >= 1) {
          poll_ge(p.flags, FPG, 31, (unsigned)s);
          poll_ge(p.flags, FH2, 63, (unsigned)s);
        }
        if (s >= R_H2) poll_ge(p.flags, FZO, 3, (unsigned)(s - 15));
      }
      __syncthreads();
      float p2v[2][4], pg1v[2][4], hpv[2][4];
      const float* pre2s = p.pre2f + (size_t)(s % R_P2) * HS;
      const float* pg1s  = p.pg1f + (size_t)((s + R_PG - 1) % R_PG) * HS;
#pragma unroll
      for (int rf = 0; rf < 2; ++rf)
#pragma unroll
        for (int r = 0; r < 4; ++r) {
          const size_t idx = (size_t)(mb + rf * 16 + q * 4 + r) * Hh + colw + lm;
          p2v[rf][r] = ldf(pre2s + idx);
          pg1v[rf][r] = (s > 0) ? ldf(pg1s + idx) : 0.f;
          hpv[rf][r] = p.h2f[idx];       // block-local plain RW
        }
      const short* h2prev = p.h2ring + (size_t)((s + R_H2 - 1) % R_H2) * HS;
      stage32(As, h2prev + (size_t)mb * Hh, tid);
      __syncthreads();
      f32x4 acc[2][2]; acc[0][0] = acc[0][1] = acc[1][0] = acc[1][1] = z4;
      pass32p(As, lm, q, P, acc);        // acc[0]=z2, acc[1]=zg
      short* h2out = p.h2ring + (size_t)(s % R_H2) * HS;
#pragma unroll
      for (int rf = 0; rf < 2; ++rf)
#pragma unroll
        for (int r = 0; r < 4; ++r) {
          const int row = mb + rf * 16 + q * 4 + r;
          const int col = colw + lm;
          const size_t idx = (size_t)row * Hh + col;
          const float u = (s == 0) ? 1.f
              : 1.f / (1.f + expf(-(acc[1][rf][r] + pg1v[rf][r])));
          const float hn = tanhf(acc[0][rf][r] + p2v[rf][r]);
          const float nv = fmaf(u, hn - hpv[rf][r], hpv[rf][r]);
          p.h2f[idx] = nv;
          const short hv = f2bf(nv);
          ST_BF16_PAIR(h2out, row, col, hv);
        }
      POST_FLAG(s + 1);
    }
  } else {                               // ============ out(ot) ============
    for (int ot = 0; ot < Tt; ++ot) {
      BPre P;
      if (wv < 2) prefillB(P, B0, st0, B1, st1, lm, q);
      if (tid < 64) {
        poll_ge(p.flags, FH2, 63, (unsigned)(ot + 1));
        poll_ge(p.flags, FPO, 3,  (unsigned)(ot + 1));
      }
      __syncthreads();
      const float* po1s = p.po1f + (size_t)(ot % R_PO) * (Bb * Oo);
      float pv[2][2][4];
      if (wv < 2) {
#pragma unroll
        for (int n = 0; n < 2; ++n)
#pragma unroll
          for (int rf = 0; rf < 2; ++rf)
#pragma unroll
            for (int r = 0; r < 4; ++r)
              pv[n][rf][r] = ldf(po1s + (size_t)(mb + rf * 16 + q * 4 + r) * Oo
                                 + colw + n * 16 + lm);
      }
      const short* h2cur = p.h2ring + (size_t)(ot % R_H2) * HS;
      stage32(As, h2cur + (size_t)mb * Hh, tid);
      __syncthreads();
      if (wv < 2) {
        f32x4 acc[2][2]; acc[0][0] = acc[0][1] = acc[1][0] = acc[1][1] = z4;
        pass32p(As, lm, q, P, acc);
#pragma unroll
        for (int n = 0; n < 2; ++n)
#pragma unroll
          for (int rf = 0; rf < 2; ++rf)
#pragma unroll
            for (int r = 0; r < 4; ++r) {
              const int row = mb + rf * 16 + q * 4 + r;
              const int col = colw + n * 16 + lm;
              p.out[(size_t)row * (Tt * Oo) + (size_t)ot * Oo + col] =
                  pv[n][rf][r] + tanhf(acc[n][rf][r] + (n ? bias1 : bias0));
            }
      }
      POST_FLAG(ot + 1);
    }
  }
}

// pre_x[t][b][j] = x[b,t,:] @ W_ih1[j,:] + b_ih1[j] + b_hh1[j]  (stored bf16)
__global__ void __launch_bounds__(256) prex_kernel(
    const float* __restrict__ x, const float* __restrict__ wih1,
    const float* __restrict__ b_ih1, const float* __restrict__ b_hh1,
    short* __restrict__ prex) {
  const int tid = threadIdx.x;
  const int lane = tid & 63;
  const int wv = tid >> 6;
  const int lm = lane & 15;
  const int q = lane >> 4;
  const int bm = blockIdx.x >> 4;
  const int bn = blockIdx.x & 15;
  const int rowbase = bm * 64;
  const int col = bn * 64 + wv * 16 + lm;

  const f32x4 z4 = {0.f, 0.f, 0.f, 0.f};
  f32x4 acc[4];
#pragma unroll
  for (int mt = 0; mt < 4; ++mt) acc[mt] = z4;

#pragma unroll
  for (int kc = 0; kc < 2; ++kc) {
    const float* bp = wih1 + col * 64 + kc * 32 + q * 8;
    bf16x8 bf;
#pragma unroll
    for (int j = 0; j < 8; ++j) bf[j] = f2bf(bp[j]);
#pragma unroll
    for (int mt = 0; mt < 4; ++mt) {
      const float* ap = x + (size_t)(rowbase + mt * 16 + lm) * 64 + kc * 32 + q * 8;
      bf16x8 af;
#pragma unroll
      for (int j = 0; j < 8; ++j) af[j] = f2bf(ap[j]);
      acc[mt] = __builtin_amdgcn_mfma_f32_16x16x32_bf16(af, bf, acc[mt], 0, 0, 0);
    }
  }
  const float bia = b_ih1[col] + b_hh1[col];
#pragma unroll
  for (int mt = 0; mt < 4; ++mt) {
#pragma unroll
    for (int r = 0; r < 4; ++r) {
      const int row = rowbase + mt * 16 + q * 4 + r;  // row = b*256 + t
      const int b  = row >> 8;
      const int tt = row & 255;
      prex[((size_t)tt * Bb + b) * Hh + col] = f2bf(acc[mt][r] + bia);
    }
  }
}

__global__ void conv_kernel(const float* __restrict__ s, short* __restrict__ d, int n) {
  int i = blockIdx.x * blockDim.x + threadIdx.x;
  const int stride = gridDim.x * blockDim.x;
  for (; i < n; i += stride) d[i] = f2bf(s[i]);
}

__global__ void init_kernel(short* h1ring, short* h2ring,
                            float* h2f, unsigned* flags) {
  const int i = blockIdx.x * blockDim.x + threadIdx.x;  // exactly 128*1024
  const size_t HS = (size_t)Bb * Hh;
  h1ring[(size_t)(R_H1 - 1) * HS + i] = 0;   // h1(-1) slot
  h2ring[(size_t)(R_H2 - 1) * HS + i] = 0;   // h2(-1) slot
  h2f[i] = 0.f;
  if (i < 256) flags[i * FLAG_STRIDE] = 0u;
}

extern "C" void kernel_launch(void* const* d_in, const int* in_sizes, int n_in,
                              void* d_out, int out_size, void* d_ws, size_t ws_size,
                              hipStream_t stream) {
  (void)in_sizes; (void)n_in; (void)out_size; (void)ws_size;
  const float* x      = (const float*)d_in[0];
  const float* W_ih1  = (const float*)d_in[1];
  const float* b_ih1  = (const float*)d_in[2];
  const float* W_hh1  = (const float*)d_in[3];
  const float* b_hh1  = (const float*)d_in[4];
  const float* W_ih2  = (const float*)d_in[5];
  const float* b_ih2  = (const float*)d_in[6];
  const float* W_hh2  = (const float*)d_in[7];
  const float* b_hh2  = (const float*)d_in[8];
  const float* Wg     = (const float*)d_in[9];
  const float* bg     = (const float*)d_in[10];
  const float* Wo1    = (const float*)d_in[11];
  const float* bo1    = (const float*)d_in[12];
  const float* Wo2    = (const float*)d_in[13];
  const float* bo2    = (const float*)d_in[14];

  char* ws = (char*)d_ws;
  size_t off = 0;
  auto alloc = [&](size_t bytes) -> void* {
    void* ptr = ws + off;
    off += (bytes + 255) & ~(size_t)255;
    return ptr;
  };
  short* whh1 = (short*)alloc((size_t)Hh * Hh * 2);
  short* wih2 = (short*)alloc((size_t)Hh * Hh * 2);
  short* whh2 = (short*)alloc((size_t)Hh * Hh * 2);
  short* wg   = (short*)alloc((size_t)Hh * 2 * Hh * 2);
  short* wo1  = (short*)alloc((size_t)Oo * Hh * 2);
  short* wo2  = (short*)alloc((size_t)Oo * Hh * 2);
  short* prex = (short*)alloc((size_t)Bb * Tt * Hh * 2);
  short* h1ring = (short*)alloc((size_t)R_H1 * Bb * Hh * 2);
  short* h2ring = (short*)alloc((size_t)R_H2 * Bb * Hh * 2);
  float* h2f  = (float*)alloc((size_t)Bb * Hh * 4);
  float* pre2f= (float*)alloc((size_t)R_P2 * Bb * Hh * 4);
  float* pg1f = (float*)alloc((size_t)R_PG * Bb * Hh * 4);
  float* po1f = (float*)alloc((size_t)R_PO * Bb * Oo * 4);
  unsigned* flags = (unsigned*)alloc(256 * FLAG_STRIDE * 4);   // 32 KB

  conv_kernel<<<1024, 256, 0, stream>>>(W_hh1, whh1, Hh * Hh);
  conv_kernel<<<1024, 256, 0, stream>>>(W_ih2, wih2, Hh * Hh);
  conv_kernel<<<1024, 256, 0, stream>>>(W_hh2, whh2, Hh * Hh);
  conv_kernel<<<2048, 256, 0, stream>>>(Wg,    wg,   Hh * 2 * Hh);
  conv_kernel<<<256,  256, 0, stream>>>(Wo1,   wo1,  Oo * Hh);
  conv_kernel<<<256,  256, 0, stream>>>(Wo2,   wo2,  Oo * Hh);
  init_kernel<<<512, 256, 0, stream>>>(h1ring, h2ring, h2f, flags);
  prex_kernel<<<8192, 256, 0, stream>>>(x, W_ih1, b_ih1, b_hh1, prex);

  RP p;
  p.h1ring = h1ring; p.h2ring = h2ring;
  p.h2f = h2f; p.pre2f = pre2f; p.pg1f = pg1f; p.po1f = po1f;
  p.prex = prex;
  p.whh1 = whh1; p.wih2 = wih2; p.whh2 = whh2;
  p.wg = wg; p.wo1 = wo1; p.wo2 = wo2;
  p.b_ih2 = b_ih2; p.b_hh2 = b_hh2;
  p.bg = bg; p.bo1 = bo1; p.bo2 = bo2;
  p.out = (float*)d_out;
  p.flags = flags;

  rnn_kernel<<<NBLK, 256, 0, stream>>>(p);
}